// Round 1
// baseline (1999.116 us; speedup 1.0000x reference)
//
#include <hip/hip_runtime.h>
#include <math.h>

#define NN 50000
#define NE 800000
#define ET (NE + NN)          // edges + self loops = 850000
#define FIN 128
#define HDIM 256
#define NHEAD 4
#define NCLS 40
#define NEG 0.2f
#define NB_SCAN ((NN + 255) / 256)   // 196

// ---------------- edge-index dtype sniff (int64 vs int32) ----------------
__global__ void detect_kernel(const int* __restrict__ ei32, int* __restrict__ flag) {
    if (threadIdx.x == 0 && blockIdx.x == 0) {
        int is64 = 1;
        for (int i = 1; i < 256; i += 2)
            if (ei32[i] != 0) { is64 = 0; break; }
        *flag = is64;
    }
}

__device__ __forceinline__ int load_node(const int* ei32, int is64, long long idx) {
    // values are < 2^31 and non-negative, so low word suffices for int64
    return is64 ? ei32[2 * idx] : ei32[idx];
}

// ---------------- CSR build ----------------
__global__ void deg_kernel(const int* __restrict__ ei32, const int* __restrict__ flag,
                           int* __restrict__ deg) {
    int e = blockIdx.x * blockDim.x + threadIdx.x;
    if (e >= ET) return;
    int is64 = *flag;
    int d = (e < NE) ? load_node(ei32, is64, (long long)NE + e) : (e - NE);
    atomicAdd(&deg[d], 1);
}

__global__ void scan1(const int* __restrict__ deg, int* __restrict__ incl,
                      int* __restrict__ bsum) {
    __shared__ int sm[256];
    int i = blockIdx.x * 256 + threadIdx.x;
    int v = (i < NN) ? deg[i] : 0;
    sm[threadIdx.x] = v;
    __syncthreads();
    for (int o = 1; o < 256; o <<= 1) {
        int add = (threadIdx.x >= o) ? sm[threadIdx.x - o] : 0;
        __syncthreads();
        sm[threadIdx.x] += add;
        __syncthreads();
    }
    if (i < NN) incl[i] = sm[threadIdx.x];
    if (threadIdx.x == 255) bsum[blockIdx.x] = sm[255];
}

__global__ void scan2(int* __restrict__ bsum) {
    __shared__ int sm[256];
    int t = threadIdx.x;
    sm[t] = (t < NB_SCAN) ? bsum[t] : 0;
    __syncthreads();
    if (t == 0) {
        int run = 0;
        for (int b = 0; b < NB_SCAN; b++) { int v = sm[b]; sm[b] = run; run += v; }
    }
    __syncthreads();
    if (t < NB_SCAN) bsum[t] = sm[t];
}

__global__ void scan3(const int* __restrict__ incl, const int* __restrict__ bsum,
                      const int* __restrict__ deg, int* __restrict__ indptr,
                      int* __restrict__ cursor) {
    int i = blockIdx.x * 256 + threadIdx.x;
    if (i < NN) {
        int v = bsum[blockIdx.x] + incl[i];
        indptr[i + 1] = v;
        cursor[i] = v - deg[i];
    }
    if (i == 0) indptr[0] = 0;
}

__global__ void fill_kernel(const int* __restrict__ ei32, const int* __restrict__ flag,
                            int* __restrict__ cursor, int* __restrict__ esrc) {
    int e = blockIdx.x * blockDim.x + threadIdx.x;
    if (e >= ET) return;
    int is64 = *flag;
    int s, d;
    if (e < NE) {
        s = load_node(ei32, is64, (long long)e);
        d = load_node(ei32, is64, (long long)NE + e);
    } else {
        s = d = e - NE;
    }
    int pos = atomicAdd(&cursor[d], 1);
    esrc[pos] = s;
}

// ---------------- GEMM: C[M,HDIM] = A[M,K] * B[K,HDIM] ----------------
__global__ __launch_bounds__(256) void gemm_kernel(const float* __restrict__ A,
                                                   const float* __restrict__ B,
                                                   float* __restrict__ C, int M, int K) {
    const int BK = 16;
    __shared__ float As[BK][65];
    __shared__ float Bs[BK][65];
    int tx = threadIdx.x & 15, ty = threadIdx.x >> 4;
    int row0 = blockIdx.y * 64, col0 = blockIdx.x * 64;
    float acc[4][4] = {};
    for (int k0 = 0; k0 < K; k0 += BK) {
#pragma unroll
        for (int i = 0; i < 4; i++) {
            int l = threadIdx.x + 256 * i;
            int r = l >> 4, c = l & 15;
            int gr = row0 + r;
            float v = 0.f;
            if (gr < M) v = A[(size_t)gr * K + k0 + c];
            As[c][r] = v;
        }
#pragma unroll
        for (int i = 0; i < 4; i++) {
            int l = threadIdx.x + 256 * i;
            int r = l >> 6, c = l & 63;
            Bs[r][c] = B[(size_t)(k0 + r) * HDIM + col0 + c];
        }
        __syncthreads();
#pragma unroll
        for (int k = 0; k < BK; k++) {
            float a[4], b[4];
#pragma unroll
            for (int i = 0; i < 4; i++) a[i] = As[k][ty + 16 * i];
#pragma unroll
            for (int j = 0; j < 4; j++) b[j] = Bs[k][tx + 16 * j];
#pragma unroll
            for (int i = 0; i < 4; i++)
#pragma unroll
                for (int j = 0; j < 4; j++) acc[i][j] += a[i] * b[j];
        }
        __syncthreads();
    }
#pragma unroll
    for (int i = 0; i < 4; i++) {
        int gr = row0 + ty + 16 * i;
        if (gr >= M) continue;
#pragma unroll
        for (int j = 0; j < 4; j++) {
            int gc = col0 + tx + 16 * j;
            C[(size_t)gr * HDIM + gc] = acc[i][j];
        }
    }
}

// ---------------- alpha_s / alpha_d: per-node per-head dot ----------------
__global__ __launch_bounds__(256) void alpha_kernel(const float* __restrict__ proj,
                                                    const float* __restrict__ a_s,
                                                    const float* __restrict__ a_d,
                                                    float* __restrict__ als,
                                                    float* __restrict__ ald) {
    int v = blockIdx.x;
    int t = threadIdx.x;
    float h = proj[(size_t)v * HDIM + t];
    float vs = h * a_s[t];
    float vd = h * a_d[t];
    for (int o = 32; o > 0; o >>= 1) {
        vs += __shfl_down(vs, o);
        vd += __shfl_down(vd, o);
    }
    if ((t & 63) == 0) {
        als[v * NHEAD + (t >> 6)] = vs;
        ald[v * NHEAD + (t >> 6)] = vd;
    }
}

// ---------------- per-dst-node softmax + weighted aggregation + bias + ELU -------
__global__ __launch_bounds__(256) void agg_kernel(const float* __restrict__ proj,
                                                  const float* __restrict__ als,
                                                  const float* __restrict__ ald,
                                                  const int* __restrict__ indptr,
                                                  const int* __restrict__ esrc,
                                                  const float* __restrict__ bias,
                                                  float* __restrict__ outf) {
    int v = blockIdx.x;
    int t = threadIdx.x;
    int head = t >> 6;
    int beg = indptr[v], end = indptr[v + 1];
    float adv = ald[v * NHEAD + head];

    float mx = -INFINITY;
    for (int i = beg; i < end; i++) {
        int s = esrc[i];
        float e = als[s * NHEAD + head] + adv;
        e = e > 0.f ? e : NEG * e;
        mx = fmaxf(mx, e);
    }
    float sum = 0.f;
    for (int i = beg; i < end; i++) {
        int s = esrc[i];
        float e = als[s * NHEAD + head] + adv;
        e = e > 0.f ? e : NEG * e;
        sum += expf(e - mx);
    }
    float inv = 1.f / (sum + 1e-16f);
    float acc = 0.f;
    for (int i = beg; i < end; i++) {
        int s = esrc[i];
        float e = als[s * NHEAD + head] + adv;
        e = e > 0.f ? e : NEG * e;
        float w = expf(e - mx) * inv;
        acc += proj[(size_t)s * HDIM + t] * w;
    }
    float r = acc + bias[t];
    r = r > 0.f ? r : expf(r) - 1.f;   // ELU
    outf[(size_t)v * HDIM + t] = r;
}

// ---------------- final linear [256->40] + log_softmax ----------------
__global__ __launch_bounds__(256) void final_kernel(const float* __restrict__ feat,
                                                    const float* __restrict__ Wl,
                                                    const float* __restrict__ bl,
                                                    float* __restrict__ out) {
    int v = blockIdx.x * 4 + (threadIdx.x >> 6);
    int lane = threadIdx.x & 63;
    if (v >= NN) return;
    float logit = -INFINITY;
    if (lane < NCLS) {
        float acc = bl[lane];
        for (int k = 0; k < HDIM; k++)
            acc += feat[(size_t)v * HDIM + k] * Wl[k * NCLS + lane];
        logit = acc;
    }
    float m = logit;
    for (int o = 32; o > 0; o >>= 1) m = fmaxf(m, __shfl_xor(m, o));
    float ex = (lane < NCLS) ? expf(logit - m) : 0.f;
    float s = ex;
    for (int o = 32; o > 0; o >>= 1) s += __shfl_xor(s, o);
    if (lane < NCLS) out[(size_t)v * NCLS + lane] = logit - m - logf(s);
}

extern "C" void kernel_launch(void* const* d_in, const int* in_sizes, int n_in,
                              void* d_out, int out_size, void* d_ws, size_t ws_size,
                              hipStream_t stream) {
    const float* x  = (const float*)d_in[0];
    const int* ei32 = (const int*)d_in[1];
    const float* W1 = (const float*)d_in[2];
    const float* as1 = (const float*)d_in[3];
    const float* ad1 = (const float*)d_in[4];
    const float* b1 = (const float*)d_in[5];
    const float* W2 = (const float*)d_in[6];
    const float* as2 = (const float*)d_in[7];
    const float* ad2 = (const float*)d_in[8];
    const float* b2 = (const float*)d_in[9];
    const float* W3 = (const float*)d_in[10];
    const float* as3 = (const float*)d_in[11];
    const float* ad3 = (const float*)d_in[12];
    const float* b3 = (const float*)d_in[13];
    const float* Wl = (const float*)d_in[14];
    const float* bl = (const float*)d_in[15];
    float* out = (float*)d_out;

    // workspace layout
    char* w = (char*)d_ws;
    float* proj = (float*)w;  w += (size_t)NN * HDIM * 4;
    float* feat = (float*)w;  w += (size_t)NN * HDIM * 4;
    float* als  = (float*)w;  w += (size_t)NN * NHEAD * 4;
    float* ald  = (float*)w;  w += (size_t)NN * NHEAD * 4;
    int* deg    = (int*)w;    w += (size_t)NN * 4;
    int* incl   = (int*)w;    w += (size_t)NN * 4;
    int* bsum   = (int*)w;    w += 256 * 4;
    int* indptr = (int*)w;    w += (size_t)(NN + 1) * 4;
    int* cursor = (int*)w;    w += (size_t)NN * 4;
    int* esrc   = (int*)w;    w += (size_t)ET * 4;
    int* flag   = (int*)w;    w += 64;

    // ---- CSR build (same edge structure for all three layers) ----
    hipMemsetAsync(deg, 0, (size_t)NN * 4, stream);
    detect_kernel<<<1, 64, 0, stream>>>(ei32, flag);
    deg_kernel<<<(ET + 255) / 256, 256, 0, stream>>>(ei32, flag, deg);
    scan1<<<NB_SCAN, 256, 0, stream>>>(deg, incl, bsum);
    scan2<<<1, 256, 0, stream>>>(bsum);
    scan3<<<NB_SCAN, 256, 0, stream>>>(incl, bsum, deg, indptr, cursor);
    fill_kernel<<<(ET + 255) / 256, 256, 0, stream>>>(ei32, flag, cursor, esrc);

    dim3 ggrid(HDIM / 64, (NN + 63) / 64);

    // ---- layer 1 ----
    gemm_kernel<<<ggrid, 256, 0, stream>>>(x, W1, proj, NN, FIN);
    alpha_kernel<<<NN, 256, 0, stream>>>(proj, as1, ad1, als, ald);
    agg_kernel<<<NN, 256, 0, stream>>>(proj, als, ald, indptr, esrc, b1, feat);
    // ---- layer 2 ----
    gemm_kernel<<<ggrid, 256, 0, stream>>>(feat, W2, proj, NN, HDIM);
    alpha_kernel<<<NN, 256, 0, stream>>>(proj, as2, ad2, als, ald);
    agg_kernel<<<NN, 256, 0, stream>>>(proj, als, ald, indptr, esrc, b2, feat);
    // ---- layer 3 ----
    gemm_kernel<<<ggrid, 256, 0, stream>>>(feat, W3, proj, NN, HDIM);
    alpha_kernel<<<NN, 256, 0, stream>>>(proj, as3, ad3, als, ald);
    agg_kernel<<<NN, 256, 0, stream>>>(proj, als, ald, indptr, esrc, b3, feat);
    // ---- final linear + log_softmax ----
    final_kernel<<<(NN + 3) / 4, 256, 0, stream>>>(feat, Wl, bl, out);
}

// Round 2
// 1100.457 us; speedup vs baseline: 1.8166x; 1.8166x over previous
//
#include <hip/hip_runtime.h>
#include <math.h>

#define NN 50000
#define NE 800000
#define ET (NE + NN)          // edges + self loops = 850000
#define FIN 128
#define HDIM 256
#define NHEAD 4
#define NCLS 40
#define NEG 0.2f
#define NB_SCAN ((NN + 255) / 256)   // 196

// ---------------- edge-index dtype sniff (int64 vs int32) ----------------
__global__ void detect_kernel(const int* __restrict__ ei32, int* __restrict__ flag) {
    if (threadIdx.x == 0 && blockIdx.x == 0) {
        int is64 = 1;
        for (int i = 1; i < 256; i += 2)
            if (ei32[i] != 0) { is64 = 0; break; }
        *flag = is64;
    }
}

__device__ __forceinline__ int load_node(const int* ei32, int is64, long long idx) {
    return is64 ? ei32[2 * idx] : ei32[idx];
}

// ---------------- CSR build ----------------
__global__ void deg_kernel(const int* __restrict__ ei32, const int* __restrict__ flag,
                           int* __restrict__ deg) {
    int e = blockIdx.x * blockDim.x + threadIdx.x;
    if (e >= ET) return;
    int is64 = *flag;
    int d = (e < NE) ? load_node(ei32, is64, (long long)NE + e) : (e - NE);
    atomicAdd(&deg[d], 1);
}

__global__ void scan1(const int* __restrict__ deg, int* __restrict__ incl,
                      int* __restrict__ bsum) {
    __shared__ int sm[256];
    int i = blockIdx.x * 256 + threadIdx.x;
    int v = (i < NN) ? deg[i] : 0;
    sm[threadIdx.x] = v;
    __syncthreads();
    for (int o = 1; o < 256; o <<= 1) {
        int add = (threadIdx.x >= o) ? sm[threadIdx.x - o] : 0;
        __syncthreads();
        sm[threadIdx.x] += add;
        __syncthreads();
    }
    if (i < NN) incl[i] = sm[threadIdx.x];
    if (threadIdx.x == 255) bsum[blockIdx.x] = sm[255];
}

__global__ void scan2(int* __restrict__ bsum) {
    __shared__ int sm[256];
    int t = threadIdx.x;
    sm[t] = (t < NB_SCAN) ? bsum[t] : 0;
    __syncthreads();
    if (t == 0) {
        int run = 0;
        for (int b = 0; b < NB_SCAN; b++) { int v = sm[b]; sm[b] = run; run += v; }
    }
    __syncthreads();
    if (t < NB_SCAN) bsum[t] = sm[t];
}

__global__ void scan3(const int* __restrict__ incl, const int* __restrict__ bsum,
                      const int* __restrict__ deg, int* __restrict__ indptr,
                      int* __restrict__ cursor) {
    int i = blockIdx.x * 256 + threadIdx.x;
    if (i < NN) {
        int v = bsum[blockIdx.x] + incl[i];
        indptr[i + 1] = v;
        cursor[i] = v - deg[i];
    }
    if (i == 0) indptr[0] = 0;
}

__global__ void fill_kernel(const int* __restrict__ ei32, const int* __restrict__ flag,
                            int* __restrict__ cursor, int* __restrict__ esrc) {
    int e = blockIdx.x * blockDim.x + threadIdx.x;
    if (e >= ET) return;
    int is64 = *flag;
    int s, d;
    if (e < NE) {
        s = load_node(ei32, is64, (long long)e);
        d = load_node(ei32, is64, (long long)NE + e);
    } else {
        s = d = e - NE;
    }
    int pos = atomicAdd(&cursor[d], 1);
    esrc[pos] = s;
}

// ---------------- GEMM: C[M,HDIM] = A[M,K] * B[K,HDIM] ----------------
__global__ __launch_bounds__(256) void gemm_kernel(const float* __restrict__ A,
                                                   const float* __restrict__ B,
                                                   float* __restrict__ C, int M, int K) {
    const int BK = 16;
    __shared__ float As[BK][65];
    __shared__ float Bs[BK][65];
    int tx = threadIdx.x & 15, ty = threadIdx.x >> 4;
    int row0 = blockIdx.y * 64, col0 = blockIdx.x * 64;
    float acc[4][4] = {};
    for (int k0 = 0; k0 < K; k0 += BK) {
#pragma unroll
        for (int i = 0; i < 4; i++) {
            int l = threadIdx.x + 256 * i;
            int r = l >> 4, c = l & 15;
            int gr = row0 + r;
            float v = 0.f;
            if (gr < M) v = A[(size_t)gr * K + k0 + c];
            As[c][r] = v;
        }
#pragma unroll
        for (int i = 0; i < 4; i++) {
            int l = threadIdx.x + 256 * i;
            int r = l >> 6, c = l & 63;
            Bs[r][c] = B[(size_t)(k0 + r) * HDIM + col0 + c];
        }
        __syncthreads();
#pragma unroll
        for (int k = 0; k < BK; k++) {
            float a[4], b[4];
#pragma unroll
            for (int i = 0; i < 4; i++) a[i] = As[k][ty + 16 * i];
#pragma unroll
            for (int j = 0; j < 4; j++) b[j] = Bs[k][tx + 16 * j];
#pragma unroll
            for (int i = 0; i < 4; i++)
#pragma unroll
                for (int j = 0; j < 4; j++) acc[i][j] += a[i] * b[j];
        }
        __syncthreads();
    }
#pragma unroll
    for (int i = 0; i < 4; i++) {
        int gr = row0 + ty + 16 * i;
        if (gr >= M) continue;
#pragma unroll
        for (int j = 0; j < 4; j++) {
            int gc = col0 + tx + 16 * j;
            C[(size_t)gr * HDIM + gc] = acc[i][j];
        }
    }
}

// ---------------- alpha_s / alpha_d: per-node per-head dot ----------------
__global__ __launch_bounds__(256) void alpha_kernel(const float* __restrict__ proj,
                                                    const float* __restrict__ a_s,
                                                    const float* __restrict__ a_d,
                                                    float* __restrict__ als,
                                                    float* __restrict__ ald) {
    int v = blockIdx.x;
    int t = threadIdx.x;
    float h = proj[(size_t)v * HDIM + t];
    float vs = h * a_s[t];
    float vd = h * a_d[t];
    for (int o = 32; o > 0; o >>= 1) {
        vs += __shfl_down(vs, o);
        vd += __shfl_down(vd, o);
    }
    if ((t & 63) == 0) {
        als[v * NHEAD + (t >> 6)] = vs;
        ald[v * NHEAD + (t >> 6)] = vd;
    }
}

// ---- fused per-dst softmax + aggregation: weights computed ONCE per (edge,head) ----
__global__ __launch_bounds__(256) void agg_kernel(const float* __restrict__ proj,
                                                  const float* __restrict__ als,
                                                  const float* __restrict__ ald,
                                                  const int* __restrict__ indptr,
                                                  const int* __restrict__ esrc,
                                                  const float* __restrict__ bias,
                                                  float* __restrict__ outf) {
    __shared__ float smax[NHEAD];
    __shared__ float ssum[NHEAD];
    __shared__ float wlds[64][5];   // stride-5 words -> conflict-free
    __shared__ int   slds[64];

    int v = blockIdx.x;
    int t = threadIdx.x;
    int lane = t & 63;
    int wid = t >> 6;               // wave id == head id == feature-group id
    int beg = indptr[v], end = indptr[v + 1];
    float adv = ald[v * NHEAD + wid];

    // ---- phase 1: online (max, sumexp) per head; wave `wid` owns head `wid` ----
    float m = -INFINITY, ss = 0.f;
    for (int i = beg + lane; i < end; i += 64) {
        int s = esrc[i];
        float e = als[s * NHEAD + wid] + adv;
        e = e > 0.f ? e : NEG * e;
        if (e > m) {
            ss = ss * __expf(m - e) + 1.f;   // m=-inf: ss*0+1 with ss=0 -> 1
            m = e;
        } else {
            ss += __expf(e - m);
        }
    }
#pragma unroll
    for (int o = 32; o > 0; o >>= 1) {
        float m2 = __shfl_xor(m, o);
        float s2 = __shfl_xor(ss, o);
        float mn = fmaxf(m, m2);
        float a = (m == mn) ? ss : ss * __expf(m - mn);
        float b = (m2 == mn) ? s2 : s2 * __expf(m2 - mn);
        m = mn;
        ss = a + b;
    }
    if (lane == 0) {
        smax[wid] = m;
        ssum[wid] = ss;
    }
    __syncthreads();

    float mh = smax[wid];
    float inv = 1.f / (ssum[wid] + 1e-16f);

    // ---- phase 2: chunked weights in LDS + gather-FMA ----
    float acc = 0.f;
    for (int c = beg; c < end; c += 64) {
        int n = min(64, end - c);
        if (lane < n) {
            int s = esrc[c + lane];
            if (wid == 0) slds[lane] = s;
            float e = als[s * NHEAD + wid] + adv;
            e = e > 0.f ? e : NEG * e;
            wlds[lane][wid] = __expf(e - mh) * inv;
        }
        __syncthreads();
#pragma unroll 4
        for (int j = 0; j < n; j++) {
            int s = slds[j];
            acc += proj[(size_t)s * HDIM + t] * wlds[j][wid];
        }
        __syncthreads();
    }

    float r = acc + bias[t];
    r = r > 0.f ? r : __expf(r) - 1.f;   // ELU
    outf[(size_t)v * HDIM + t] = r;
}

// ---------------- final linear [256->40] + log_softmax ----------------
__global__ __launch_bounds__(256) void final_kernel(const float* __restrict__ feat,
                                                    const float* __restrict__ Wl,
                                                    const float* __restrict__ bl,
                                                    float* __restrict__ out) {
    int v = blockIdx.x * 4 + (threadIdx.x >> 6);
    int lane = threadIdx.x & 63;
    if (v >= NN) return;
    float logit = -INFINITY;
    if (lane < NCLS) {
        float acc = bl[lane];
        for (int k = 0; k < HDIM; k++)
            acc += feat[(size_t)v * HDIM + k] * Wl[k * NCLS + lane];
        logit = acc;
    }
    float m = logit;
    for (int o = 32; o > 0; o >>= 1) m = fmaxf(m, __shfl_xor(m, o));
    float ex = (lane < NCLS) ? __expf(logit - m) : 0.f;
    float s = ex;
    for (int o = 32; o > 0; o >>= 1) s += __shfl_xor(s, o);
    if (lane < NCLS) out[(size_t)v * NCLS + lane] = logit - m - __logf(s);
}

extern "C" void kernel_launch(void* const* d_in, const int* in_sizes, int n_in,
                              void* d_out, int out_size, void* d_ws, size_t ws_size,
                              hipStream_t stream) {
    const float* x  = (const float*)d_in[0];
    const int* ei32 = (const int*)d_in[1];
    const float* W1 = (const float*)d_in[2];
    const float* as1 = (const float*)d_in[3];
    const float* ad1 = (const float*)d_in[4];
    const float* b1 = (const float*)d_in[5];
    const float* W2 = (const float*)d_in[6];
    const float* as2 = (const float*)d_in[7];
    const float* ad2 = (const float*)d_in[8];
    const float* b2 = (const float*)d_in[9];
    const float* W3 = (const float*)d_in[10];
    const float* as3 = (const float*)d_in[11];
    const float* ad3 = (const float*)d_in[12];
    const float* b3 = (const float*)d_in[13];
    const float* Wl = (const float*)d_in[14];
    const float* bl = (const float*)d_in[15];
    float* out = (float*)d_out;

    // workspace layout
    char* w = (char*)d_ws;
    float* proj = (float*)w;  w += (size_t)NN * HDIM * 4;
    float* feat = (float*)w;  w += (size_t)NN * HDIM * 4;
    float* als  = (float*)w;  w += (size_t)NN * NHEAD * 4;
    float* ald  = (float*)w;  w += (size_t)NN * NHEAD * 4;
    int* deg    = (int*)w;    w += (size_t)NN * 4;
    int* incl   = (int*)w;    w += (size_t)NN * 4;
    int* bsum   = (int*)w;    w += 256 * 4;
    int* indptr = (int*)w;    w += (size_t)(NN + 1) * 4;
    int* cursor = (int*)w;    w += (size_t)NN * 4;
    int* esrc   = (int*)w;    w += (size_t)ET * 4;
    int* flag   = (int*)w;    w += 64;

    // ---- CSR build (same edge structure for all three layers) ----
    hipMemsetAsync(deg, 0, (size_t)NN * 4, stream);
    detect_kernel<<<1, 64, 0, stream>>>(ei32, flag);
    deg_kernel<<<(ET + 255) / 256, 256, 0, stream>>>(ei32, flag, deg);
    scan1<<<NB_SCAN, 256, 0, stream>>>(deg, incl, bsum);
    scan2<<<1, 256, 0, stream>>>(bsum);
    scan3<<<NB_SCAN, 256, 0, stream>>>(incl, bsum, deg, indptr, cursor);
    fill_kernel<<<(ET + 255) / 256, 256, 0, stream>>>(ei32, flag, cursor, esrc);

    dim3 ggrid(HDIM / 64, (NN + 63) / 64);

    // ---- layer 1 ----
    gemm_kernel<<<ggrid, 256, 0, stream>>>(x, W1, proj, NN, FIN);
    alpha_kernel<<<NN, 256, 0, stream>>>(proj, as1, ad1, als, ald);
    agg_kernel<<<NN, 256, 0, stream>>>(proj, als, ald, indptr, esrc, b1, feat);
    // ---- layer 2 ----
    gemm_kernel<<<ggrid, 256, 0, stream>>>(feat, W2, proj, NN, HDIM);
    alpha_kernel<<<NN, 256, 0, stream>>>(proj, as2, ad2, als, ald);
    agg_kernel<<<NN, 256, 0, stream>>>(proj, als, ald, indptr, esrc, b2, feat);
    // ---- layer 3 ----
    gemm_kernel<<<ggrid, 256, 0, stream>>>(feat, W3, proj, NN, HDIM);
    alpha_kernel<<<NN, 256, 0, stream>>>(proj, as3, ad3, als, ald);
    agg_kernel<<<NN, 256, 0, stream>>>(proj, als, ald, indptr, esrc, b3, feat);
    // ---- final linear + log_softmax ----
    final_kernel<<<(NN + 3) / 4, 256, 0, stream>>>(feat, Wl, bl, out);
}

// Round 3
// 979.113 us; speedup vs baseline: 2.0418x; 1.1239x over previous
//
#include <hip/hip_runtime.h>
#include <math.h>

#define NN 50000
#define NE 800000
#define ET (NE + NN)          // edges + self loops = 850000
#define FIN 128
#define HDIM 256
#define NHEAD 4
#define NCLS 40
#define NEG 0.2f
#define NB_SCAN ((NN + 255) / 256)   // 196

// ---------------- edge-index dtype sniff (int64 vs int32) ----------------
__global__ void detect_kernel(const int* __restrict__ ei32, int* __restrict__ flag) {
    if (threadIdx.x == 0 && blockIdx.x == 0) {
        int is64 = 1;
        for (int i = 1; i < 256; i += 2)
            if (ei32[i] != 0) { is64 = 0; break; }
        *flag = is64;
    }
}

__device__ __forceinline__ int load_node(const int* ei32, int is64, long long idx) {
    return is64 ? ei32[2 * idx] : ei32[idx];
}

// ---------------- CSR build ----------------
__global__ void deg_kernel(const int* __restrict__ ei32, const int* __restrict__ flag,
                           int* __restrict__ deg) {
    int e = blockIdx.x * blockDim.x + threadIdx.x;
    if (e >= ET) return;
    int is64 = *flag;
    int d = (e < NE) ? load_node(ei32, is64, (long long)NE + e) : (e - NE);
    atomicAdd(&deg[d], 1);
}

__global__ void scan1(const int* __restrict__ deg, int* __restrict__ incl,
                      int* __restrict__ bsum) {
    __shared__ int sm[256];
    int i = blockIdx.x * 256 + threadIdx.x;
    int v = (i < NN) ? deg[i] : 0;
    sm[threadIdx.x] = v;
    __syncthreads();
    for (int o = 1; o < 256; o <<= 1) {
        int add = (threadIdx.x >= o) ? sm[threadIdx.x - o] : 0;
        __syncthreads();
        sm[threadIdx.x] += add;
        __syncthreads();
    }
    if (i < NN) incl[i] = sm[threadIdx.x];
    if (threadIdx.x == 255) bsum[blockIdx.x] = sm[255];
}

__global__ void scan2(int* __restrict__ bsum) {
    __shared__ int sm[256];
    int t = threadIdx.x;
    sm[t] = (t < NB_SCAN) ? bsum[t] : 0;
    __syncthreads();
    if (t == 0) {
        int run = 0;
        for (int b = 0; b < NB_SCAN; b++) { int v = sm[b]; sm[b] = run; run += v; }
    }
    __syncthreads();
    if (t < NB_SCAN) bsum[t] = sm[t];
}

__global__ void scan3(const int* __restrict__ incl, const int* __restrict__ bsum,
                      const int* __restrict__ deg, int* __restrict__ indptr,
                      int* __restrict__ cursor) {
    int i = blockIdx.x * 256 + threadIdx.x;
    if (i < NN) {
        int v = bsum[blockIdx.x] + incl[i];
        indptr[i + 1] = v;
        cursor[i] = v - deg[i];
    }
    if (i == 0) indptr[0] = 0;
}

__global__ void fill_kernel(const int* __restrict__ ei32, const int* __restrict__ flag,
                            int* __restrict__ cursor, int* __restrict__ esrc) {
    int e = blockIdx.x * blockDim.x + threadIdx.x;
    if (e >= ET) return;
    int is64 = *flag;
    int s, d;
    if (e < NE) {
        s = load_node(ei32, is64, (long long)e);
        d = load_node(ei32, is64, (long long)NE + e);
    } else {
        s = d = e - NE;
    }
    int pos = atomicAdd(&cursor[d], 1);
    esrc[pos] = s;
}

// ---------------- GEMM: C[M,HDIM] = A[M,K] * B[K,HDIM] ----------------
__global__ __launch_bounds__(256) void gemm_kernel(const float* __restrict__ A,
                                                   const float* __restrict__ B,
                                                   float* __restrict__ C, int M, int K) {
    const int BK = 16;
    __shared__ float As[BK][65];
    __shared__ float Bs[BK][65];
    int tx = threadIdx.x & 15, ty = threadIdx.x >> 4;
    int row0 = blockIdx.y * 64, col0 = blockIdx.x * 64;
    float acc[4][4] = {};
    for (int k0 = 0; k0 < K; k0 += BK) {
#pragma unroll
        for (int i = 0; i < 4; i++) {
            int l = threadIdx.x + 256 * i;
            int r = l >> 4, c = l & 15;
            int gr = row0 + r;
            float v = 0.f;
            if (gr < M) v = A[(size_t)gr * K + k0 + c];
            As[c][r] = v;
        }
#pragma unroll
        for (int i = 0; i < 4; i++) {
            int l = threadIdx.x + 256 * i;
            int r = l >> 6, c = l & 63;
            Bs[r][c] = B[(size_t)(k0 + r) * HDIM + col0 + c];
        }
        __syncthreads();
#pragma unroll
        for (int k = 0; k < BK; k++) {
            float a[4], b[4];
#pragma unroll
            for (int i = 0; i < 4; i++) a[i] = As[k][ty + 16 * i];
#pragma unroll
            for (int j = 0; j < 4; j++) b[j] = Bs[k][tx + 16 * j];
#pragma unroll
            for (int i = 0; i < 4; i++)
#pragma unroll
                for (int j = 0; j < 4; j++) acc[i][j] += a[i] * b[j];
        }
        __syncthreads();
    }
#pragma unroll
    for (int i = 0; i < 4; i++) {
        int gr = row0 + ty + 16 * i;
        if (gr >= M) continue;
#pragma unroll
        for (int j = 0; j < 4; j++) {
            int gc = col0 + tx + 16 * j;
            C[(size_t)gr * HDIM + gc] = acc[i][j];
        }
    }
}

// ---------------- alpha_s / alpha_d: per-node per-head dot ----------------
__global__ __launch_bounds__(256) void alpha_kernel(const float* __restrict__ proj,
                                                    const float* __restrict__ a_s,
                                                    const float* __restrict__ a_d,
                                                    float* __restrict__ als,
                                                    float* __restrict__ ald) {
    int v = blockIdx.x;
    int t = threadIdx.x;
    float h = proj[(size_t)v * HDIM + t];
    float vs = h * a_s[t];
    float vd = h * a_d[t];
    for (int o = 32; o > 0; o >>= 1) {
        vs += __shfl_down(vs, o);
        vd += __shfl_down(vd, o);
    }
    if ((t & 63) == 0) {
        als[v * NHEAD + (t >> 6)] = vs;
        ald[v * NHEAD + (t >> 6)] = vd;
    }
}

// ---- fused per-dst softmax + aggregation: weights computed ONCE per (edge,head) ----
__global__ __launch_bounds__(256) void agg_kernel(const float* __restrict__ proj,
                                                  const float* __restrict__ als,
                                                  const float* __restrict__ ald,
                                                  const int* __restrict__ indptr,
                                                  const int* __restrict__ esrc,
                                                  const float* __restrict__ bias,
                                                  float* __restrict__ outf) {
    __shared__ float smax[NHEAD];
    __shared__ float ssum[NHEAD];
    __shared__ float wlds[64][5];   // stride-5 words -> conflict-free
    __shared__ int   slds[64];

    int v = blockIdx.x;
    int t = threadIdx.x;
    int lane = t & 63;
    int wid = t >> 6;               // wave id == head id == feature-group id
    int beg = indptr[v], end = indptr[v + 1];
    float adv = ald[v * NHEAD + wid];

    // ---- phase 1: online (max, sumexp) per head; wave `wid` owns head `wid` ----
    float m = -INFINITY, ss = 0.f;
    for (int i = beg + lane; i < end; i += 64) {
        int s = esrc[i];
        float e = als[s * NHEAD + wid] + adv;
        e = e > 0.f ? e : NEG * e;
        if (e > m) {
            ss = ss * __expf(m - e) + 1.f;   // m=-inf: ss*0+1 with ss=0 -> 1
            m = e;
        } else {
            ss += __expf(e - m);
        }
    }
#pragma unroll
    for (int o = 32; o > 0; o >>= 1) {
        float m2 = __shfl_xor(m, o);
        float s2 = __shfl_xor(ss, o);
        float mn = fmaxf(m, m2);
        float a = (m == mn) ? ss : ss * __expf(m - mn);
        float b = (m2 == mn) ? s2 : s2 * __expf(m2 - mn);
        m = mn;
        ss = a + b;
    }
    if (lane == 0) {
        smax[wid] = m;
        ssum[wid] = ss;
    }
    __syncthreads();

    float mh = smax[wid];
    float inv = 1.f / (ssum[wid] + 1e-16f);

    // ---- phase 2: chunked weights in LDS + gather-FMA ----
    float acc = 0.f;
    for (int c = beg; c < end; c += 64) {
        int n = min(64, end - c);
        if (lane < n) {
            int s = esrc[c + lane];
            if (wid == 0) slds[lane] = s;
            float e = als[s * NHEAD + wid] + adv;
            e = e > 0.f ? e : NEG * e;
            wlds[lane][wid] = __expf(e - mh) * inv;
        }
        __syncthreads();
#pragma unroll 4
        for (int j = 0; j < n; j++) {
            int s = slds[j];
            acc += proj[(size_t)s * HDIM + t] * wlds[j][wid];
        }
        __syncthreads();
    }

    float r = acc + bias[t];
    r = r > 0.f ? r : __expf(r) - 1.f;   // ELU
    outf[(size_t)v * HDIM + t] = r;
}

// ---- final linear [256->40] + log_softmax, tiled GEMM with class dim padded to 64 ----
__global__ __launch_bounds__(256) void final_kernel(const float* __restrict__ feat,
                                                    const float* __restrict__ Wl,
                                                    const float* __restrict__ bl,
                                                    float* __restrict__ out) {
    const int BK = 16;
    __shared__ float As[BK][65];
    __shared__ float Bs[BK][65];
    int tx = threadIdx.x & 15, ty = threadIdx.x >> 4;
    int row0 = blockIdx.x * 64;
    float acc[4][4] = {};
    for (int k0 = 0; k0 < HDIM; k0 += BK) {
#pragma unroll
        for (int i = 0; i < 4; i++) {
            int l = threadIdx.x + 256 * i;
            int r = l >> 4, c = l & 15;
            int gr = row0 + r;
            float v = 0.f;
            if (gr < NN) v = feat[(size_t)gr * HDIM + k0 + c];
            As[c][r] = v;
        }
#pragma unroll
        for (int i = 0; i < 4; i++) {
            int l = threadIdx.x + 256 * i;
            int r = l >> 6, c = l & 63;
            Bs[r][c] = (c < NCLS) ? Wl[(size_t)(k0 + r) * NCLS + c] : 0.f;
        }
        __syncthreads();
#pragma unroll
        for (int k = 0; k < BK; k++) {
            float a[4], b[4];
#pragma unroll
            for (int i = 0; i < 4; i++) a[i] = As[k][ty + 16 * i];
#pragma unroll
            for (int j = 0; j < 4; j++) b[j] = Bs[k][tx + 16 * j];
#pragma unroll
            for (int i = 0; i < 4; i++)
#pragma unroll
                for (int j = 0; j < 4; j++) acc[i][j] += a[i] * b[j];
        }
        __syncthreads();
    }
    // epilogue: cols tx, tx+16 valid everywhere; tx+32 valid iff tx<8; tx+48 never.
    float b0 = bl[tx], b1 = bl[tx + 16], b2 = (tx < 8) ? bl[tx + 32] : 0.f;
#pragma unroll
    for (int i = 0; i < 4; i++) {
        int gr = row0 + ty + 16 * i;
        if (gr >= NN) continue;
        float l0 = acc[i][0] + b0;
        float l1 = acc[i][1] + b1;
        float l2 = (tx < 8) ? acc[i][2] + b2 : -INFINITY;
        float m = fmaxf(fmaxf(l0, l1), l2);
#pragma unroll
        for (int o = 8; o > 0; o >>= 1) m = fmaxf(m, __shfl_xor(m, o));
        float s = __expf(l0 - m) + __expf(l1 - m) + ((tx < 8) ? __expf(l2 - m) : 0.f);
#pragma unroll
        for (int o = 8; o > 0; o >>= 1) s += __shfl_xor(s, o);
        float lse = m + __logf(s);
        out[(size_t)gr * NCLS + tx] = l0 - lse;
        out[(size_t)gr * NCLS + tx + 16] = l1 - lse;
        if (tx < 8) out[(size_t)gr * NCLS + tx + 32] = l2 - lse;
    }
}

extern "C" void kernel_launch(void* const* d_in, const int* in_sizes, int n_in,
                              void* d_out, int out_size, void* d_ws, size_t ws_size,
                              hipStream_t stream) {
    const float* x  = (const float*)d_in[0];
    const int* ei32 = (const int*)d_in[1];
    const float* W1 = (const float*)d_in[2];
    const float* as1 = (const float*)d_in[3];
    const float* ad1 = (const float*)d_in[4];
    const float* b1 = (const float*)d_in[5];
    const float* W2 = (const float*)d_in[6];
    const float* as2 = (const float*)d_in[7];
    const float* ad2 = (const float*)d_in[8];
    const float* b2 = (const float*)d_in[9];
    const float* W3 = (const float*)d_in[10];
    const float* as3 = (const float*)d_in[11];
    const float* ad3 = (const float*)d_in[12];
    const float* b3 = (const float*)d_in[13];
    const float* Wl = (const float*)d_in[14];
    const float* bl = (const float*)d_in[15];
    float* out = (float*)d_out;

    // workspace layout
    char* w = (char*)d_ws;
    float* proj = (float*)w;  w += (size_t)NN * HDIM * 4;
    float* feat = (float*)w;  w += (size_t)NN * HDIM * 4;
    float* als  = (float*)w;  w += (size_t)NN * NHEAD * 4;
    float* ald  = (float*)w;  w += (size_t)NN * NHEAD * 4;
    int* deg    = (int*)w;    w += (size_t)NN * 4;
    int* incl   = (int*)w;    w += (size_t)NN * 4;
    int* bsum   = (int*)w;    w += 256 * 4;
    int* indptr = (int*)w;    w += (size_t)(NN + 1) * 4;
    int* cursor = (int*)w;    w += (size_t)NN * 4;
    int* esrc   = (int*)w;    w += (size_t)ET * 4;
    int* flag   = (int*)w;    w += 64;

    // ---- CSR build (same edge structure for all three layers) ----
    hipMemsetAsync(deg, 0, (size_t)NN * 4, stream);
    detect_kernel<<<1, 64, 0, stream>>>(ei32, flag);
    deg_kernel<<<(ET + 255) / 256, 256, 0, stream>>>(ei32, flag, deg);
    scan1<<<NB_SCAN, 256, 0, stream>>>(deg, incl, bsum);
    scan2<<<1, 256, 0, stream>>>(bsum);
    scan3<<<NB_SCAN, 256, 0, stream>>>(incl, bsum, deg, indptr, cursor);
    fill_kernel<<<(ET + 255) / 256, 256, 0, stream>>>(ei32, flag, cursor, esrc);

    dim3 ggrid(HDIM / 64, (NN + 63) / 64);

    // ---- layer 1 ----
    gemm_kernel<<<ggrid, 256, 0, stream>>>(x, W1, proj, NN, FIN);
    alpha_kernel<<<NN, 256, 0, stream>>>(proj, as1, ad1, als, ald);
    agg_kernel<<<NN, 256, 0, stream>>>(proj, als, ald, indptr, esrc, b1, feat);
    // ---- layer 2 ----
    gemm_kernel<<<ggrid, 256, 0, stream>>>(feat, W2, proj, NN, HDIM);
    alpha_kernel<<<NN, 256, 0, stream>>>(proj, as2, ad2, als, ald);
    agg_kernel<<<NN, 256, 0, stream>>>(proj, als, ald, indptr, esrc, b2, feat);
    // ---- layer 3 ----
    gemm_kernel<<<ggrid, 256, 0, stream>>>(feat, W3, proj, NN, HDIM);
    alpha_kernel<<<NN, 256, 0, stream>>>(proj, as3, ad3, als, ald);
    agg_kernel<<<NN, 256, 0, stream>>>(proj, als, ald, indptr, esrc, b3, feat);
    // ---- final linear + log_softmax (fused) ----
    final_kernel<<<(NN + 63) / 64, 256, 0, stream>>>(feat, Wl, bl, out);
}

// Round 4
// 929.276 us; speedup vs baseline: 2.1513x; 1.0536x over previous
//
#include <hip/hip_runtime.h>
#include <math.h>

#define NN 50000
#define NE 800000
#define ET (NE + NN)          // edges + self loops = 850000
#define FIN 128
#define HDIM 256
#define NHEAD 4
#define NCLS 40
#define NEG 0.2f
#define NB_SCAN ((NN + 255) / 256)   // 196

// ---------------- edge-index dtype sniff (int64 vs int32) ----------------
__global__ void detect_kernel(const int* __restrict__ ei32, int* __restrict__ flag) {
    if (threadIdx.x == 0 && blockIdx.x == 0) {
        int is64 = 1;
        for (int i = 1; i < 256; i += 2)
            if (ei32[i] != 0) { is64 = 0; break; }
        *flag = is64;
    }
}

__device__ __forceinline__ int load_node(const int* ei32, int is64, long long idx) {
    return is64 ? ei32[2 * idx] : ei32[idx];
}

// ---------------- CSR build ----------------
__global__ void deg_kernel(const int* __restrict__ ei32, const int* __restrict__ flag,
                           int* __restrict__ deg) {
    int e = blockIdx.x * blockDim.x + threadIdx.x;
    if (e >= ET) return;
    int is64 = *flag;
    int d = (e < NE) ? load_node(ei32, is64, (long long)NE + e) : (e - NE);
    atomicAdd(&deg[d], 1);
}

__global__ void scan1(const int* __restrict__ deg, int* __restrict__ incl,
                      int* __restrict__ bsum) {
    __shared__ int sm[256];
    int i = blockIdx.x * 256 + threadIdx.x;
    int v = (i < NN) ? deg[i] : 0;
    sm[threadIdx.x] = v;
    __syncthreads();
    for (int o = 1; o < 256; o <<= 1) {
        int add = (threadIdx.x >= o) ? sm[threadIdx.x - o] : 0;
        __syncthreads();
        sm[threadIdx.x] += add;
        __syncthreads();
    }
    if (i < NN) incl[i] = sm[threadIdx.x];
    if (threadIdx.x == 255) bsum[blockIdx.x] = sm[255];
}

__global__ void scan2(int* __restrict__ bsum) {
    __shared__ int sm[256];
    int t = threadIdx.x;
    sm[t] = (t < NB_SCAN) ? bsum[t] : 0;
    __syncthreads();
    if (t == 0) {
        int run = 0;
        for (int b = 0; b < NB_SCAN; b++) { int v = sm[b]; sm[b] = run; run += v; }
    }
    __syncthreads();
    if (t < NB_SCAN) bsum[t] = sm[t];
}

__global__ void scan3(const int* __restrict__ incl, const int* __restrict__ bsum,
                      const int* __restrict__ deg, int* __restrict__ indptr,
                      int* __restrict__ cursor) {
    int i = blockIdx.x * 256 + threadIdx.x;
    if (i < NN) {
        int v = bsum[blockIdx.x] + incl[i];
        indptr[i + 1] = v;
        cursor[i] = v - deg[i];
    }
    if (i == 0) indptr[0] = 0;
}

__global__ void fill_kernel(const int* __restrict__ ei32, const int* __restrict__ flag,
                            int* __restrict__ cursor, int* __restrict__ esrc) {
    int e = blockIdx.x * blockDim.x + threadIdx.x;
    if (e >= ET) return;
    int is64 = *flag;
    int s, d;
    if (e < NE) {
        s = load_node(ei32, is64, (long long)e);
        d = load_node(ei32, is64, (long long)NE + e);
    } else {
        s = d = e - NE;
    }
    int pos = atomicAdd(&cursor[d], 1);
    esrc[pos] = s;
}

// ---------------- GEMM: C[M,HDIM] = A[M,K] * B[K,HDIM] ----------------
__global__ __launch_bounds__(256) void gemm_kernel(const float* __restrict__ A,
                                                   const float* __restrict__ B,
                                                   float* __restrict__ C, int M, int K) {
    const int BK = 16;
    __shared__ float As[BK][65];
    __shared__ float Bs[BK][65];
    int tx = threadIdx.x & 15, ty = threadIdx.x >> 4;
    int row0 = blockIdx.y * 64, col0 = blockIdx.x * 64;
    float acc[4][4] = {};
    for (int k0 = 0; k0 < K; k0 += BK) {
#pragma unroll
        for (int i = 0; i < 4; i++) {
            int l = threadIdx.x + 256 * i;
            int r = l >> 4, c = l & 15;
            int gr = row0 + r;
            float v = 0.f;
            if (gr < M) v = A[(size_t)gr * K + k0 + c];
            As[c][r] = v;
        }
#pragma unroll
        for (int i = 0; i < 4; i++) {
            int l = threadIdx.x + 256 * i;
            int r = l >> 6, c = l & 63;
            Bs[r][c] = B[(size_t)(k0 + r) * HDIM + col0 + c];
        }
        __syncthreads();
#pragma unroll
        for (int k = 0; k < BK; k++) {
            float a[4], b[4];
#pragma unroll
            for (int i = 0; i < 4; i++) a[i] = As[k][ty + 16 * i];
#pragma unroll
            for (int j = 0; j < 4; j++) b[j] = Bs[k][tx + 16 * j];
#pragma unroll
            for (int i = 0; i < 4; i++)
#pragma unroll
                for (int j = 0; j < 4; j++) acc[i][j] += a[i] * b[j];
        }
        __syncthreads();
    }
#pragma unroll
    for (int i = 0; i < 4; i++) {
        int gr = row0 + ty + 16 * i;
        if (gr >= M) continue;
#pragma unroll
        for (int j = 0; j < 4; j++) {
            int gc = col0 + tx + 16 * j;
            C[(size_t)gr * HDIM + gc] = acc[i][j];
        }
    }
}

// ---------------- alpha_s / alpha_d: per-node per-head dot ----------------
__global__ __launch_bounds__(256) void alpha_kernel(const float* __restrict__ proj,
                                                    const float* __restrict__ a_s,
                                                    const float* __restrict__ a_d,
                                                    float* __restrict__ als,
                                                    float* __restrict__ ald) {
    int v = blockIdx.x;
    int t = threadIdx.x;
    float h = proj[(size_t)v * HDIM + t];
    float vs = h * a_s[t];
    float vd = h * a_d[t];
    for (int o = 32; o > 0; o >>= 1) {
        vs += __shfl_down(vs, o);
        vd += __shfl_down(vd, o);
    }
    if ((t & 63) == 0) {
        als[v * NHEAD + (t >> 6)] = vs;
        ald[v * NHEAD + (t >> 6)] = vd;
    }
}

// ---- agg: one WAVE per node, float4 gather, weight computed once per (edge,head) ----
__global__ __launch_bounds__(256) void agg_kernel(const float* __restrict__ proj,
                                                  const float* __restrict__ als,
                                                  const float* __restrict__ ald,
                                                  const int* __restrict__ indptr,
                                                  const int* __restrict__ esrc,
                                                  const float* __restrict__ bias,
                                                  float* __restrict__ outf) {
    int wid = threadIdx.x >> 6;
    int v = blockIdx.x * 4 + wid;
    if (v >= NN) return;
    int lane = threadIdx.x & 63;
    int h = lane >> 4;          // head owned by this lane (features 4*lane..4*lane+3)
    int sub = lane & 15;
    int beg = indptr[v], end = indptr[v + 1];
    float adv = ald[v * NHEAD + h];

    // ---- phase 1: 16 lanes per head, online (max,sumexp) over edges strided 16 ----
    float m = -INFINITY, ss = 0.f;
    for (int i = beg + sub; i < end; i += 16) {
        int s = esrc[i];
        float e = als[s * NHEAD + h] + adv;
        e = e > 0.f ? e : NEG * e;
        if (e > m) {
            ss = ss * __expf(m - e) + 1.f;
            m = e;
        } else {
            ss += __expf(e - m);
        }
    }
#pragma unroll
    for (int o = 8; o > 0; o >>= 1) {
        float m2 = __shfl_xor(m, o);
        float s2 = __shfl_xor(ss, o);
        float mn = fmaxf(m, m2);
        float a = (m == mn) ? ss : ss * __expf(m - mn);
        float b = (m2 == mn) ? s2 : s2 * __expf(m2 - mn);
        m = mn;
        ss = a + b;
    }
    float inv = 1.f / (ss + 1e-16f);

    // ---- phase 2: chunks of 16 edges; lane (h,sub) computes w(edge c+sub, head h) ----
    float4 acc = make_float4(0.f, 0.f, 0.f, 0.f);
    for (int c = beg; c < end; c += 16) {
        int n = min(16, end - c);
        float wreg = 0.f;
        int sreg = 0;
        if (sub < n) {
            sreg = esrc[c + sub];
            float e = als[sreg * NHEAD + h] + adv;
            e = e > 0.f ? e : NEG * e;
            wreg = __expf(e - m) * inv;
        }
        for (int j = 0; j < n; j++) {
            float w = __shfl(wreg, (h << 4) | j);
            int s = __shfl(sreg, j);   // lanes 0..15 hold esrc[c..c+n)
            const float4 p = *(const float4*)(proj + (size_t)s * HDIM + (lane << 2));
            acc.x += p.x * w;
            acc.y += p.y * w;
            acc.z += p.z * w;
            acc.w += p.w * w;
        }
    }

    const float4 b4 = *(const float4*)(bias + (lane << 2));
    float4 r;
    r.x = acc.x + b4.x;
    r.y = acc.y + b4.y;
    r.z = acc.z + b4.z;
    r.w = acc.w + b4.w;
    r.x = r.x > 0.f ? r.x : __expf(r.x) - 1.f;
    r.y = r.y > 0.f ? r.y : __expf(r.y) - 1.f;
    r.z = r.z > 0.f ? r.z : __expf(r.z) - 1.f;
    r.w = r.w > 0.f ? r.w : __expf(r.w) - 1.f;
    *(float4*)(outf + (size_t)v * HDIM + (lane << 2)) = r;
}

// ---- final linear [256->40] + log_softmax, tiled GEMM with class dim padded to 64 ----
__global__ __launch_bounds__(256) void final_kernel(const float* __restrict__ feat,
                                                    const float* __restrict__ Wl,
                                                    const float* __restrict__ bl,
                                                    float* __restrict__ out) {
    const int BK = 16;
    __shared__ float As[BK][65];
    __shared__ float Bs[BK][65];
    int tx = threadIdx.x & 15, ty = threadIdx.x >> 4;
    int row0 = blockIdx.x * 64;
    float acc[4][4] = {};
    for (int k0 = 0; k0 < HDIM; k0 += BK) {
#pragma unroll
        for (int i = 0; i < 4; i++) {
            int l = threadIdx.x + 256 * i;
            int r = l >> 4, c = l & 15;
            int gr = row0 + r;
            float v = 0.f;
            if (gr < NN) v = feat[(size_t)gr * HDIM + k0 + c];
            As[c][r] = v;
        }
#pragma unroll
        for (int i = 0; i < 4; i++) {
            int l = threadIdx.x + 256 * i;
            int r = l >> 6, c = l & 63;
            Bs[r][c] = (c < NCLS) ? Wl[(size_t)(k0 + r) * NCLS + c] : 0.f;
        }
        __syncthreads();
#pragma unroll
        for (int k = 0; k < BK; k++) {
            float a[4], b[4];
#pragma unroll
            for (int i = 0; i < 4; i++) a[i] = As[k][ty + 16 * i];
#pragma unroll
            for (int j = 0; j < 4; j++) b[j] = Bs[k][tx + 16 * j];
#pragma unroll
            for (int i = 0; i < 4; i++)
#pragma unroll
                for (int j = 0; j < 4; j++) acc[i][j] += a[i] * b[j];
        }
        __syncthreads();
    }
    // epilogue: cols tx, tx+16 valid everywhere; tx+32 valid iff tx<8; tx+48 never.
    float b0 = bl[tx], b1 = bl[tx + 16], b2 = (tx < 8) ? bl[tx + 32] : 0.f;
#pragma unroll
    for (int i = 0; i < 4; i++) {
        int gr = row0 + ty + 16 * i;
        if (gr >= NN) continue;
        float l0 = acc[i][0] + b0;
        float l1 = acc[i][1] + b1;
        float l2 = (tx < 8) ? acc[i][2] + b2 : -INFINITY;
        float m = fmaxf(fmaxf(l0, l1), l2);
#pragma unroll
        for (int o = 8; o > 0; o >>= 1) m = fmaxf(m, __shfl_xor(m, o));
        float s = __expf(l0 - m) + __expf(l1 - m) + ((tx < 8) ? __expf(l2 - m) : 0.f);
#pragma unroll
        for (int o = 8; o > 0; o >>= 1) s += __shfl_xor(s, o);
        float lse = m + __logf(s);
        out[(size_t)gr * NCLS + tx] = l0 - lse;
        out[(size_t)gr * NCLS + tx + 16] = l1 - lse;
        if (tx < 8) out[(size_t)gr * NCLS + tx + 32] = l2 - lse;
    }
}

extern "C" void kernel_launch(void* const* d_in, const int* in_sizes, int n_in,
                              void* d_out, int out_size, void* d_ws, size_t ws_size,
                              hipStream_t stream) {
    const float* x  = (const float*)d_in[0];
    const int* ei32 = (const int*)d_in[1];
    const float* W1 = (const float*)d_in[2];
    const float* as1 = (const float*)d_in[3];
    const float* ad1 = (const float*)d_in[4];
    const float* b1 = (const float*)d_in[5];
    const float* W2 = (const float*)d_in[6];
    const float* as2 = (const float*)d_in[7];
    const float* ad2 = (const float*)d_in[8];
    const float* b2 = (const float*)d_in[9];
    const float* W3 = (const float*)d_in[10];
    const float* as3 = (const float*)d_in[11];
    const float* ad3 = (const float*)d_in[12];
    const float* b3 = (const float*)d_in[13];
    const float* Wl = (const float*)d_in[14];
    const float* bl = (const float*)d_in[15];
    float* out = (float*)d_out;

    // workspace layout
    char* w = (char*)d_ws;
    float* proj = (float*)w;  w += (size_t)NN * HDIM * 4;
    float* feat = (float*)w;  w += (size_t)NN * HDIM * 4;
    float* als  = (float*)w;  w += (size_t)NN * NHEAD * 4;
    float* ald  = (float*)w;  w += (size_t)NN * NHEAD * 4;
    int* deg    = (int*)w;    w += (size_t)NN * 4;
    int* incl   = (int*)w;    w += (size_t)NN * 4;
    int* bsum   = (int*)w;    w += 256 * 4;
    int* indptr = (int*)w;    w += (size_t)(NN + 1) * 4;
    int* cursor = (int*)w;    w += (size_t)NN * 4;
    int* esrc   = (int*)w;    w += (size_t)ET * 4;
    int* flag   = (int*)w;    w += 64;

    // ---- CSR build (same edge structure for all three layers) ----
    hipMemsetAsync(deg, 0, (size_t)NN * 4, stream);
    detect_kernel<<<1, 64, 0, stream>>>(ei32, flag);
    deg_kernel<<<(ET + 255) / 256, 256, 0, stream>>>(ei32, flag, deg);
    scan1<<<NB_SCAN, 256, 0, stream>>>(deg, incl, bsum);
    scan2<<<1, 256, 0, stream>>>(bsum);
    scan3<<<NB_SCAN, 256, 0, stream>>>(incl, bsum, deg, indptr, cursor);
    fill_kernel<<<(ET + 255) / 256, 256, 0, stream>>>(ei32, flag, cursor, esrc);

    dim3 ggrid(HDIM / 64, (NN + 63) / 64);
    int agrid = (NN + 3) / 4;

    // ---- layer 1 ----
    gemm_kernel<<<ggrid, 256, 0, stream>>>(x, W1, proj, NN, FIN);
    alpha_kernel<<<NN, 256, 0, stream>>>(proj, as1, ad1, als, ald);
    agg_kernel<<<agrid, 256, 0, stream>>>(proj, als, ald, indptr, esrc, b1, feat);
    // ---- layer 2 ----
    gemm_kernel<<<ggrid, 256, 0, stream>>>(feat, W2, proj, NN, HDIM);
    alpha_kernel<<<NN, 256, 0, stream>>>(proj, as2, ad2, als, ald);
    agg_kernel<<<agrid, 256, 0, stream>>>(proj, als, ald, indptr, esrc, b2, feat);
    // ---- layer 3 ----
    gemm_kernel<<<ggrid, 256, 0, stream>>>(feat, W3, proj, NN, HDIM);
    alpha_kernel<<<NN, 256, 0, stream>>>(proj, as3, ad3, als, ald);
    agg_kernel<<<agrid, 256, 0, stream>>>(proj, als, ald, indptr, esrc, b3, feat);
    // ---- final linear + log_softmax (fused) ----
    final_kernel<<<(NN + 63) / 64, 256, 0, stream>>>(feat, Wl, bl, out);
}

// Round 5
// 680.223 us; speedup vs baseline: 2.9389x; 1.3661x over previous
//
#include <hip/hip_runtime.h>
#include <math.h>

#define NN 50000
#define NE 800000
#define ET (NE + NN)          // edges + self loops = 850000
#define FIN 128
#define HDIM 256
#define NHEAD 4
#define NCLS 40
#define NEG 0.2f
#define NB_SCAN ((NN + 255) / 256)   // 196

typedef short bf16x8 __attribute__((ext_vector_type(8)));
typedef float f32x4 __attribute__((ext_vector_type(4)));

__device__ __forceinline__ unsigned short f2b(float f) {
    unsigned int u = __float_as_uint(f);
    unsigned int r = (u + 0x7fffu + ((u >> 16) & 1u)) >> 16;
    return (unsigned short)r;
}
__device__ __forceinline__ float b2f(unsigned short u) {
    unsigned int x = ((unsigned int)u) << 16;
    return __uint_as_float(x);
}

// ---------------- edge-index dtype sniff (int64 vs int32) ----------------
__global__ void detect_kernel(const int* __restrict__ ei32, int* __restrict__ flag) {
    if (threadIdx.x == 0 && blockIdx.x == 0) {
        int is64 = 1;
        for (int i = 1; i < 256; i += 2)
            if (ei32[i] != 0) { is64 = 0; break; }
        *flag = is64;
    }
}

__device__ __forceinline__ int load_node(const int* ei32, int is64, long long idx) {
    return is64 ? ei32[2 * idx] : ei32[idx];
}

// ---------------- CSR build ----------------
__global__ void deg_kernel(const int* __restrict__ ei32, const int* __restrict__ flag,
                           int* __restrict__ deg) {
    int e = blockIdx.x * blockDim.x + threadIdx.x;
    if (e >= ET) return;
    int is64 = *flag;
    int d = (e < NE) ? load_node(ei32, is64, (long long)NE + e) : (e - NE);
    atomicAdd(&deg[d], 1);
}

__global__ void scan1(const int* __restrict__ deg, int* __restrict__ incl,
                      int* __restrict__ bsum) {
    __shared__ int sm[256];
    int i = blockIdx.x * 256 + threadIdx.x;
    int v = (i < NN) ? deg[i] : 0;
    sm[threadIdx.x] = v;
    __syncthreads();
    for (int o = 1; o < 256; o <<= 1) {
        int add = (threadIdx.x >= o) ? sm[threadIdx.x - o] : 0;
        __syncthreads();
        sm[threadIdx.x] += add;
        __syncthreads();
    }
    if (i < NN) incl[i] = sm[threadIdx.x];
    if (threadIdx.x == 255) bsum[blockIdx.x] = sm[255];
}

__global__ void scan2(int* __restrict__ bsum) {
    __shared__ int sm[256];
    int t = threadIdx.x;
    sm[t] = (t < NB_SCAN) ? bsum[t] : 0;
    __syncthreads();
    if (t == 0) {
        int run = 0;
        for (int b = 0; b < NB_SCAN; b++) { int v = sm[b]; sm[b] = run; run += v; }
    }
    __syncthreads();
    if (t < NB_SCAN) bsum[t] = sm[t];
}

__global__ void scan3(const int* __restrict__ incl, const int* __restrict__ bsum,
                      const int* __restrict__ deg, int* __restrict__ indptr,
                      int* __restrict__ cursor) {
    int i = blockIdx.x * 256 + threadIdx.x;
    if (i < NN) {
        int v = bsum[blockIdx.x] + incl[i];
        indptr[i + 1] = v;
        cursor[i] = v - deg[i];
    }
    if (i == 0) indptr[0] = 0;
}

__global__ void fill_kernel(const int* __restrict__ ei32, const int* __restrict__ flag,
                            int* __restrict__ cursor, int* __restrict__ esrc) {
    int e = blockIdx.x * blockDim.x + threadIdx.x;
    if (e >= ET) return;
    int is64 = *flag;
    int s, d;
    if (e < NE) {
        s = load_node(ei32, is64, (long long)e);
        d = load_node(ei32, is64, (long long)NE + e);
    } else {
        s = d = e - NE;
    }
    int pos = atomicAdd(&cursor[d], 1);
    esrc[pos] = s;
}

// ---------------- f32 -> bf16 elementwise (n divisible by 8) ----------------
__global__ __launch_bounds__(256) void conv_kernel(const float* __restrict__ in,
                                                   unsigned short* __restrict__ out, int n) {
    int i = (blockIdx.x * 256 + threadIdx.x) * 8;
    if (i + 8 > n) return;
    float4 f0 = *(const float4*)(in + i);
    float4 f1 = *(const float4*)(in + i + 4);
    ushort4 a, b;
    a.x = f2b(f0.x); a.y = f2b(f0.y); a.z = f2b(f0.z); a.w = f2b(f0.w);
    b.x = f2b(f1.x); b.y = f2b(f1.y); b.z = f2b(f1.z); b.w = f2b(f1.w);
    *(ushort4*)(out + i) = a;
    *(ushort4*)(out + i + 4) = b;
}

// ------- W[K][256] f32 -> Wt[256][K] bf16 (transpose + convert) -------
__global__ __launch_bounds__(256) void wconv_kernel(const float* __restrict__ W,
                                                    unsigned short* __restrict__ Wt, int K) {
    __shared__ float sm[32][33];
    int tx = threadIdx.x & 31, ty = threadIdx.x >> 5;   // 32 x 8
    int n0 = blockIdx.x * 32, k0 = blockIdx.y * 32;
#pragma unroll
    for (int j = 0; j < 4; j++)
        sm[ty + j * 8][tx] = W[(size_t)(k0 + ty + j * 8) * HDIM + n0 + tx];
    __syncthreads();
#pragma unroll
    for (int j = 0; j < 4; j++)
        Wt[(size_t)(n0 + ty + j * 8) * K + k0 + tx] = f2b(sm[tx][ty + j * 8]);
}

// ------- MFMA GEMM: C[M,256] = A[M,K](bf16) * Bt[256,K](bf16)^T, f32 accum -------
__global__ __launch_bounds__(256) void gemm_mfma(const unsigned short* __restrict__ A,
                                                 const unsigned short* __restrict__ Bt,
                                                 float* __restrict__ C, int M, int K) {
    __shared__ unsigned short As[128][72];   // stride 144 B -> 2-way bank alias (free)
    __shared__ unsigned short Bs[64][72];
    int t = threadIdx.x;
    int lane = t & 63, wid = t >> 6;
    int r0 = blockIdx.y * 128, n0 = blockIdx.x * 64;

    f32x4 acc[2][4];
#pragma unroll
    for (int m = 0; m < 2; m++)
#pragma unroll
        for (int n = 0; n < 4; n++)
            acc[m][n] = (f32x4){0.f, 0.f, 0.f, 0.f};

    int ar = t >> 1, ah = (t & 1) * 32;
    int arow = r0 + ar; if (arow > M - 1) arow = M - 1;
    const unsigned short* ga = A + (size_t)arow * K + ah;
    int bn = t >> 2, bq = (t & 3) * 16;
    const unsigned short* gb = Bt + (size_t)(n0 + bn) * K + bq;

    int fr = lane & 15;          // frag row/col within 16
    int kf = (lane >> 4) * 8;    // k-octet

    for (int k0 = 0; k0 < K; k0 += 64) {
#pragma unroll
        for (int j = 0; j < 4; j++)
            *(uint4*)&As[ar][ah + j * 8] = *(const uint4*)(ga + k0 + j * 8);
#pragma unroll
        for (int j = 0; j < 2; j++)
            *(uint4*)&Bs[bn][bq + j * 8] = *(const uint4*)(gb + k0 + j * 8);
        __syncthreads();
#pragma unroll
        for (int kk = 0; kk < 64; kk += 32) {
            bf16x8 a[2], b[4];
#pragma unroll
            for (int m = 0; m < 2; m++)
                a[m] = *(const bf16x8*)&As[wid * 32 + m * 16 + fr][kk + kf];
#pragma unroll
            for (int n = 0; n < 4; n++)
                b[n] = *(const bf16x8*)&Bs[n * 16 + fr][kk + kf];
#pragma unroll
            for (int m = 0; m < 2; m++)
#pragma unroll
                for (int n = 0; n < 4; n++)
                    acc[m][n] = __builtin_amdgcn_mfma_f32_16x16x32_bf16(a[m], b[n], acc[m][n], 0, 0, 0);
        }
        __syncthreads();
    }

    int rbase = r0 + wid * 32 + (lane >> 4) * 4;
    int cbase = n0 + fr;
#pragma unroll
    for (int m = 0; m < 2; m++)
#pragma unroll
        for (int n = 0; n < 4; n++)
#pragma unroll
            for (int q = 0; q < 4; q++) {
                int gr = rbase + m * 16 + q;
                if (gr < M) C[(size_t)gr * HDIM + cbase + n * 16] = acc[m][n][q];
            }
}

// ---------------- alpha_s / alpha_d: per-node per-head dot ----------------
__global__ __launch_bounds__(256) void alpha_kernel(const float* __restrict__ proj,
                                                    const float* __restrict__ a_s,
                                                    const float* __restrict__ a_d,
                                                    float* __restrict__ als,
                                                    float* __restrict__ ald) {
    int v = blockIdx.x;
    int t = threadIdx.x;
    float h = proj[(size_t)v * HDIM + t];
    float vs = h * a_s[t];
    float vd = h * a_d[t];
    for (int o = 32; o > 0; o >>= 1) {
        vs += __shfl_down(vs, o);
        vd += __shfl_down(vd, o);
    }
    if ((t & 63) == 0) {
        als[v * NHEAD + (t >> 6)] = vs;
        ald[v * NHEAD + (t >> 6)] = vd;
    }
}

// ---- agg: one WAVE per node, float4 gather; writes bf16 features ----
__global__ __launch_bounds__(256) void agg_kernel(const float* __restrict__ proj,
                                                  const float* __restrict__ als,
                                                  const float* __restrict__ ald,
                                                  const int* __restrict__ indptr,
                                                  const int* __restrict__ esrc,
                                                  const float* __restrict__ bias,
                                                  unsigned short* __restrict__ featb) {
    int wid = threadIdx.x >> 6;
    int v = blockIdx.x * 4 + wid;
    if (v >= NN) return;
    int lane = threadIdx.x & 63;
    int h = lane >> 4;
    int sub = lane & 15;
    int beg = indptr[v], end = indptr[v + 1];
    float adv = ald[v * NHEAD + h];

    float m = -INFINITY, ss = 0.f;
    for (int i = beg + sub; i < end; i += 16) {
        int s = esrc[i];
        float e = als[s * NHEAD + h] + adv;
        e = e > 0.f ? e : NEG * e;
        if (e > m) {
            ss = ss * __expf(m - e) + 1.f;
            m = e;
        } else {
            ss += __expf(e - m);
        }
    }
#pragma unroll
    for (int o = 8; o > 0; o >>= 1) {
        float m2 = __shfl_xor(m, o);
        float s2 = __shfl_xor(ss, o);
        float mn = fmaxf(m, m2);
        float a = (m == mn) ? ss : ss * __expf(m - mn);
        float b = (m2 == mn) ? s2 : s2 * __expf(m2 - mn);
        m = mn;
        ss = a + b;
    }
    float inv = 1.f / (ss + 1e-16f);

    float4 acc = make_float4(0.f, 0.f, 0.f, 0.f);
    for (int c = beg; c < end; c += 16) {
        int n = min(16, end - c);
        float wreg = 0.f;
        int sreg = 0;
        if (sub < n) {
            sreg = esrc[c + sub];
            float e = als[sreg * NHEAD + h] + adv;
            e = e > 0.f ? e : NEG * e;
            wreg = __expf(e - m) * inv;
        }
        for (int j = 0; j < n; j++) {
            float w = __shfl(wreg, (h << 4) | j);
            int s = __shfl(sreg, j);
            const float4 p = *(const float4*)(proj + (size_t)s * HDIM + (lane << 2));
            acc.x += p.x * w;
            acc.y += p.y * w;
            acc.z += p.z * w;
            acc.w += p.w * w;
        }
    }

    const float4 b4 = *(const float4*)(bias + (lane << 2));
    float4 r;
    r.x = acc.x + b4.x;
    r.y = acc.y + b4.y;
    r.z = acc.z + b4.z;
    r.w = acc.w + b4.w;
    r.x = r.x > 0.f ? r.x : __expf(r.x) - 1.f;
    r.y = r.y > 0.f ? r.y : __expf(r.y) - 1.f;
    r.z = r.z > 0.f ? r.z : __expf(r.z) - 1.f;
    r.w = r.w > 0.f ? r.w : __expf(r.w) - 1.f;
    ushort4 o4;
    o4.x = f2b(r.x); o4.y = f2b(r.y); o4.z = f2b(r.z); o4.w = f2b(r.w);
    *(ushort4*)(featb + (size_t)v * HDIM + (lane << 2)) = o4;
}

// ---- final linear [256->40] + log_softmax (bf16 features), class dim padded to 64 ----
__global__ __launch_bounds__(256) void final_kernel(const unsigned short* __restrict__ featb,
                                                    const float* __restrict__ Wl,
                                                    const float* __restrict__ bl,
                                                    float* __restrict__ out) {
    const int BK = 16;
    __shared__ float As[BK][65];
    __shared__ float Bs[BK][65];
    int tx = threadIdx.x & 15, ty = threadIdx.x >> 4;
    int row0 = blockIdx.x * 64;
    float acc[4][4] = {};
    for (int k0 = 0; k0 < HDIM; k0 += BK) {
#pragma unroll
        for (int i = 0; i < 4; i++) {
            int l = threadIdx.x + 256 * i;
            int r = l >> 4, c = l & 15;
            int gr = row0 + r;
            float v = 0.f;
            if (gr < NN) v = b2f(featb[(size_t)gr * HDIM + k0 + c]);
            As[c][r] = v;
        }
#pragma unroll
        for (int i = 0; i < 4; i++) {
            int l = threadIdx.x + 256 * i;
            int r = l >> 6, c = l & 63;
            Bs[r][c] = (c < NCLS) ? Wl[(size_t)(k0 + r) * NCLS + c] : 0.f;
        }
        __syncthreads();
#pragma unroll
        for (int k = 0; k < BK; k++) {
            float a[4], b[4];
#pragma unroll
            for (int i = 0; i < 4; i++) a[i] = As[k][ty + 16 * i];
#pragma unroll
            for (int j = 0; j < 4; j++) b[j] = Bs[k][tx + 16 * j];
#pragma unroll
            for (int i = 0; i < 4; i++)
#pragma unroll
                for (int j = 0; j < 4; j++) acc[i][j] += a[i] * b[j];
        }
        __syncthreads();
    }
    float b0 = bl[tx], b1 = bl[tx + 16], b2 = (tx < 8) ? bl[tx + 32] : 0.f;
#pragma unroll
    for (int i = 0; i < 4; i++) {
        int gr = row0 + ty + 16 * i;
        if (gr >= NN) continue;
        float l0 = acc[i][0] + b0;
        float l1 = acc[i][1] + b1;
        float l2 = (tx < 8) ? acc[i][2] + b2 : -INFINITY;
        float m = fmaxf(fmaxf(l0, l1), l2);
#pragma unroll
        for (int o = 8; o > 0; o >>= 1) m = fmaxf(m, __shfl_xor(m, o));
        float s = __expf(l0 - m) + __expf(l1 - m) + ((tx < 8) ? __expf(l2 - m) : 0.f);
#pragma unroll
        for (int o = 8; o > 0; o >>= 1) s += __shfl_xor(s, o);
        float lse = m + __logf(s);
        out[(size_t)gr * NCLS + tx] = l0 - lse;
        out[(size_t)gr * NCLS + tx + 16] = l1 - lse;
        if (tx < 8) out[(size_t)gr * NCLS + tx + 32] = l2 - lse;
    }
}

extern "C" void kernel_launch(void* const* d_in, const int* in_sizes, int n_in,
                              void* d_out, int out_size, void* d_ws, size_t ws_size,
                              hipStream_t stream) {
    const float* x  = (const float*)d_in[0];
    const int* ei32 = (const int*)d_in[1];
    const float* W1 = (const float*)d_in[2];
    const float* as1 = (const float*)d_in[3];
    const float* ad1 = (const float*)d_in[4];
    const float* b1 = (const float*)d_in[5];
    const float* W2 = (const float*)d_in[6];
    const float* as2 = (const float*)d_in[7];
    const float* ad2 = (const float*)d_in[8];
    const float* b2 = (const float*)d_in[9];
    const float* W3 = (const float*)d_in[10];
    const float* as3 = (const float*)d_in[11];
    const float* ad3 = (const float*)d_in[12];
    const float* b3 = (const float*)d_in[13];
    const float* Wl = (const float*)d_in[14];
    const float* bl = (const float*)d_in[15];
    float* out = (float*)d_out;

    // workspace layout
    char* w = (char*)d_ws;
    float* proj = (float*)w;            w += (size_t)NN * HDIM * 4;
    unsigned short* featb = (unsigned short*)w;  w += (size_t)NN * HDIM * 2;
    unsigned short* xb    = (unsigned short*)w;  w += (size_t)NN * FIN * 2;
    unsigned short* Wt1b  = (unsigned short*)w;  w += (size_t)HDIM * FIN * 2;
    unsigned short* Wt2b  = (unsigned short*)w;  w += (size_t)HDIM * HDIM * 2;
    unsigned short* Wt3b  = (unsigned short*)w;  w += (size_t)HDIM * HDIM * 2;
    float* als  = (float*)w;  w += (size_t)NN * NHEAD * 4;
    float* ald  = (float*)w;  w += (size_t)NN * NHEAD * 4;
    int* deg    = (int*)w;    w += (size_t)NN * 4;
    int* incl   = (int*)w;    w += (size_t)NN * 4;
    int* bsum   = (int*)w;    w += 256 * 4;
    int* indptr = (int*)w;    w += (size_t)(NN + 1) * 4;
    int* cursor = (int*)w;    w += (size_t)NN * 4;
    int* esrc   = (int*)w;    w += (size_t)ET * 4;
    int* flag   = (int*)w;    w += 64;

    // ---- one-time conversions ----
    conv_kernel<<<(NN * FIN / 8 + 255) / 256, 256, 0, stream>>>(x, xb, NN * FIN);
    wconv_kernel<<<dim3(8, FIN / 32), 256, 0, stream>>>(W1, Wt1b, FIN);
    wconv_kernel<<<dim3(8, HDIM / 32), 256, 0, stream>>>(W2, Wt2b, HDIM);
    wconv_kernel<<<dim3(8, HDIM / 32), 256, 0, stream>>>(W3, Wt3b, HDIM);

    // ---- CSR build (same edge structure for all three layers) ----
    hipMemsetAsync(deg, 0, (size_t)NN * 4, stream);
    detect_kernel<<<1, 64, 0, stream>>>(ei32, flag);
    deg_kernel<<<(ET + 255) / 256, 256, 0, stream>>>(ei32, flag, deg);
    scan1<<<NB_SCAN, 256, 0, stream>>>(deg, incl, bsum);
    scan2<<<1, 256, 0, stream>>>(bsum);
    scan3<<<NB_SCAN, 256, 0, stream>>>(incl, bsum, deg, indptr, cursor);
    fill_kernel<<<(ET + 255) / 256, 256, 0, stream>>>(ei32, flag, cursor, esrc);

    dim3 ggrid(HDIM / 64, (NN + 127) / 128);
    int agrid = (NN + 3) / 4;

    // ---- layer 1 ----
    gemm_mfma<<<ggrid, 256, 0, stream>>>(xb, Wt1b, proj, NN, FIN);
    alpha_kernel<<<NN, 256, 0, stream>>>(proj, as1, ad1, als, ald);
    agg_kernel<<<agrid, 256, 0, stream>>>(proj, als, ald, indptr, esrc, b1, featb);
    // ---- layer 2 ----
    gemm_mfma<<<ggrid, 256, 0, stream>>>(featb, Wt2b, proj, NN, HDIM);
    alpha_kernel<<<NN, 256, 0, stream>>>(proj, as2, ad2, als, ald);
    agg_kernel<<<agrid, 256, 0, stream>>>(proj, als, ald, indptr, esrc, b2, featb);
    // ---- layer 3 ----
    gemm_mfma<<<ggrid, 256, 0, stream>>>(featb, Wt3b, proj, NN, HDIM);
    alpha_kernel<<<NN, 256, 0, stream>>>(proj, as3, ad3, als, ald);
    agg_kernel<<<agrid, 256, 0, stream>>>(proj, als, ald, indptr, esrc, b3, featb);
    // ---- final linear + log_softmax (fused) ----
    final_kernel<<<(NN + 63) / 64, 256, 0, stream>>>(featb, Wl, bl, out);
}

// Round 6
// 488.426 us; speedup vs baseline: 4.0930x; 1.3927x over previous
//
#include <hip/hip_runtime.h>
#include <math.h>

#define NN 50000
#define NE 800000
#define ET (NE + NN)          // edges + self loops = 850000
#define FIN 128
#define HDIM 256
#define NHEAD 4
#define NCLS 40
#define NEG 0.2f
#define NB_SCAN ((NN + 255) / 256)   // 196

typedef short bf16x8 __attribute__((ext_vector_type(8)));
typedef float f32x4 __attribute__((ext_vector_type(4)));

__device__ __forceinline__ unsigned short f2b(float f) {
    unsigned int u = __float_as_uint(f);
    unsigned int r = (u + 0x7fffu + ((u >> 16) & 1u)) >> 16;
    return (unsigned short)r;
}
__device__ __forceinline__ float b2f(unsigned short u) {
    unsigned int x = ((unsigned int)u) << 16;
    return __uint_as_float(x);
}

// ---------------- edge-index dtype sniff (int64 vs int32) ----------------
__global__ void detect_kernel(const int* __restrict__ ei32, int* __restrict__ flag) {
    if (threadIdx.x == 0 && blockIdx.x == 0) {
        int is64 = 1;
        for (int i = 1; i < 256; i += 2)
            if (ei32[i] != 0) { is64 = 0; break; }
        *flag = is64;
    }
}

__device__ __forceinline__ int load_node(const int* ei32, int is64, long long idx) {
    return is64 ? ei32[2 * idx] : ei32[idx];
}

// ---------------- CSR build ----------------
__global__ void deg_kernel(const int* __restrict__ ei32, const int* __restrict__ flag,
                           int* __restrict__ deg) {
    int e = blockIdx.x * blockDim.x + threadIdx.x;
    if (e >= ET) return;
    int is64 = *flag;
    int d = (e < NE) ? load_node(ei32, is64, (long long)NE + e) : (e - NE);
    atomicAdd(&deg[d], 1);
}

__global__ void scan1(const int* __restrict__ deg, int* __restrict__ incl,
                      int* __restrict__ bsum) {
    __shared__ int sm[256];
    int i = blockIdx.x * 256 + threadIdx.x;
    int v = (i < NN) ? deg[i] : 0;
    sm[threadIdx.x] = v;
    __syncthreads();
    for (int o = 1; o < 256; o <<= 1) {
        int add = (threadIdx.x >= o) ? sm[threadIdx.x - o] : 0;
        __syncthreads();
        sm[threadIdx.x] += add;
        __syncthreads();
    }
    if (i < NN) incl[i] = sm[threadIdx.x];
    if (threadIdx.x == 255) bsum[blockIdx.x] = sm[255];
}

__global__ void scan2(int* __restrict__ bsum) {
    __shared__ int sm[256];
    int t = threadIdx.x;
    sm[t] = (t < NB_SCAN) ? bsum[t] : 0;
    __syncthreads();
    if (t == 0) {
        int run = 0;
        for (int b = 0; b < NB_SCAN; b++) { int v = sm[b]; sm[b] = run; run += v; }
    }
    __syncthreads();
    if (t < NB_SCAN) bsum[t] = sm[t];
}

__global__ void scan3(const int* __restrict__ incl, const int* __restrict__ bsum,
                      const int* __restrict__ deg, int* __restrict__ indptr,
                      int* __restrict__ cursor) {
    int i = blockIdx.x * 256 + threadIdx.x;
    if (i < NN) {
        int v = bsum[blockIdx.x] + incl[i];
        indptr[i + 1] = v;
        cursor[i] = v - deg[i];
    }
    if (i == 0) indptr[0] = 0;
}

__global__ void fill_kernel(const int* __restrict__ ei32, const int* __restrict__ flag,
                            int* __restrict__ cursor, int* __restrict__ esrc) {
    int e = blockIdx.x * blockDim.x + threadIdx.x;
    if (e >= ET) return;
    int is64 = *flag;
    int s, d;
    if (e < NE) {
        s = load_node(ei32, is64, (long long)e);
        d = load_node(ei32, is64, (long long)NE + e);
    } else {
        s = d = e - NE;
    }
    int pos = atomicAdd(&cursor[d], 1);
    esrc[pos] = s;
}

// ---------------- f32 -> bf16 elementwise (n divisible by 8) ----------------
__global__ __launch_bounds__(256) void conv_kernel(const float* __restrict__ in,
                                                   unsigned short* __restrict__ out, int n) {
    int i = (blockIdx.x * 256 + threadIdx.x) * 8;
    if (i + 8 > n) return;
    float4 f0 = *(const float4*)(in + i);
    float4 f1 = *(const float4*)(in + i + 4);
    ushort4 a, b;
    a.x = f2b(f0.x); a.y = f2b(f0.y); a.z = f2b(f0.z); a.w = f2b(f0.w);
    b.x = f2b(f1.x); b.y = f2b(f1.y); b.z = f2b(f1.z); b.w = f2b(f1.w);
    *(ushort4*)(out + i) = a;
    *(ushort4*)(out + i + 4) = b;
}

// ------- W[K][256] f32 -> Wt[256][K] bf16 (transpose + convert) -------
__global__ __launch_bounds__(256) void wconv_kernel(const float* __restrict__ W,
                                                    unsigned short* __restrict__ Wt, int K) {
    __shared__ float sm[32][33];
    int tx = threadIdx.x & 31, ty = threadIdx.x >> 5;   // 32 x 8
    int n0 = blockIdx.x * 32, k0 = blockIdx.y * 32;
#pragma unroll
    for (int j = 0; j < 4; j++)
        sm[ty + j * 8][tx] = W[(size_t)(k0 + ty + j * 8) * HDIM + n0 + tx];
    __syncthreads();
#pragma unroll
    for (int j = 0; j < 4; j++)
        Wt[(size_t)(n0 + ty + j * 8) * K + k0 + tx] = f2b(sm[tx][ty + j * 8]);
}

// ------- MFMA GEMM + fused alpha: Cb[M,256](bf16) = A*Bt^T; als/ald per (row, head) -------
// block col-tile (64 cols) == one head exactly, so alpha reduction is block-local.
__global__ __launch_bounds__(256) void gemm_mfma(const unsigned short* __restrict__ A,
                                                 const unsigned short* __restrict__ Bt,
                                                 unsigned short* __restrict__ Cb,
                                                 const float* __restrict__ a_s,
                                                 const float* __restrict__ a_d,
                                                 float* __restrict__ als,
                                                 float* __restrict__ ald,
                                                 int M, int K) {
    __shared__ unsigned short As[128][72];   // stride 144 B -> 2-way bank alias (free)
    __shared__ unsigned short Bs[64][72];
    int t = threadIdx.x;
    int lane = t & 63, wid = t >> 6;
    int r0 = blockIdx.y * 128, n0 = blockIdx.x * 64;

    f32x4 acc[2][4];
#pragma unroll
    for (int m = 0; m < 2; m++)
#pragma unroll
        for (int n = 0; n < 4; n++)
            acc[m][n] = (f32x4){0.f, 0.f, 0.f, 0.f};

    int ar = t >> 1, ah = (t & 1) * 32;
    int arow = r0 + ar; if (arow > M - 1) arow = M - 1;
    const unsigned short* ga = A + (size_t)arow * K + ah;
    int bn = t >> 2, bq = (t & 3) * 16;
    const unsigned short* gb = Bt + (size_t)(n0 + bn) * K + bq;

    int fr = lane & 15;          // frag row/col within 16
    int kf = (lane >> 4) * 8;    // k-octet

    for (int k0 = 0; k0 < K; k0 += 64) {
#pragma unroll
        for (int j = 0; j < 4; j++)
            *(uint4*)&As[ar][ah + j * 8] = *(const uint4*)(ga + k0 + j * 8);
#pragma unroll
        for (int j = 0; j < 2; j++)
            *(uint4*)&Bs[bn][bq + j * 8] = *(const uint4*)(gb + k0 + j * 8);
        __syncthreads();
#pragma unroll
        for (int kk = 0; kk < 64; kk += 32) {
            bf16x8 a[2], b[4];
#pragma unroll
            for (int m = 0; m < 2; m++)
                a[m] = *(const bf16x8*)&As[wid * 32 + m * 16 + fr][kk + kf];
#pragma unroll
            for (int n = 0; n < 4; n++)
                b[n] = *(const bf16x8*)&Bs[n * 16 + fr][kk + kf];
#pragma unroll
            for (int m = 0; m < 2; m++)
#pragma unroll
                for (int n = 0; n < 4; n++)
                    acc[m][n] = __builtin_amdgcn_mfma_f32_16x16x32_bf16(a[m], b[n], acc[m][n], 0, 0, 0);
        }
        __syncthreads();
    }

    int rbase = r0 + wid * 32 + (lane >> 4) * 4;
    int cbase = n0 + fr;
    int head = n0 >> 6;
    float asv[4], adv[4];
#pragma unroll
    for (int n = 0; n < 4; n++) {
        asv[n] = a_s[cbase + n * 16];
        adv[n] = a_d[cbase + n * 16];
    }
#pragma unroll
    for (int m = 0; m < 2; m++)
#pragma unroll
        for (int q = 0; q < 4; q++) {
            int gr = rbase + m * 16 + q;
            float vs = 0.f, vd = 0.f;
#pragma unroll
            for (int n = 0; n < 4; n++) {
                float v = acc[m][n][q];
                vs += v * asv[n];
                vd += v * adv[n];
                if (gr < M) Cb[(size_t)gr * HDIM + cbase + n * 16] = f2b(v);
            }
#pragma unroll
            for (int o = 8; o > 0; o >>= 1) {
                vs += __shfl_xor(vs, o);
                vd += __shfl_xor(vd, o);
            }
            if (fr == 0 && gr < M) {
                als[gr * NHEAD + head] = vs;
                ald[gr * NHEAD + head] = vd;
            }
        }
}

// ---- agg: one WAVE per node, bf16 gather (512 B/row); writes bf16 features ----
__global__ __launch_bounds__(256) void agg_kernel(const unsigned short* __restrict__ projb,
                                                  const float* __restrict__ als,
                                                  const float* __restrict__ ald,
                                                  const int* __restrict__ indptr,
                                                  const int* __restrict__ esrc,
                                                  const float* __restrict__ bias,
                                                  unsigned short* __restrict__ featb) {
    int wid = threadIdx.x >> 6;
    int v = blockIdx.x * 4 + wid;
    if (v >= NN) return;
    int lane = threadIdx.x & 63;
    int h = lane >> 4;
    int sub = lane & 15;
    int beg = indptr[v], end = indptr[v + 1];
    float adv = ald[v * NHEAD + h];

    float m = -INFINITY, ss = 0.f;
    for (int i = beg + sub; i < end; i += 16) {
        int s = esrc[i];
        float e = als[s * NHEAD + h] + adv;
        e = e > 0.f ? e : NEG * e;
        if (e > m) {
            ss = ss * __expf(m - e) + 1.f;
            m = e;
        } else {
            ss += __expf(e - m);
        }
    }
#pragma unroll
    for (int o = 8; o > 0; o >>= 1) {
        float m2 = __shfl_xor(m, o);
        float s2 = __shfl_xor(ss, o);
        float mn = fmaxf(m, m2);
        float a = (m == mn) ? ss : ss * __expf(m - mn);
        float b = (m2 == mn) ? s2 : s2 * __expf(m2 - mn);
        m = mn;
        ss = a + b;
    }
    float inv = 1.f / (ss + 1e-16f);

    float4 acc = make_float4(0.f, 0.f, 0.f, 0.f);
    for (int c = beg; c < end; c += 16) {
        int n = min(16, end - c);
        float wreg = 0.f;
        int sreg = 0;
        if (sub < n) {
            sreg = esrc[c + sub];
            float e = als[sreg * NHEAD + h] + adv;
            e = e > 0.f ? e : NEG * e;
            wreg = __expf(e - m) * inv;
        }
        for (int j = 0; j < n; j++) {
            float w = __shfl(wreg, (h << 4) | j);
            int s = __shfl(sreg, j);
            const ushort4 p = *(const ushort4*)(projb + (size_t)s * HDIM + (lane << 2));
            acc.x += b2f(p.x) * w;
            acc.y += b2f(p.y) * w;
            acc.z += b2f(p.z) * w;
            acc.w += b2f(p.w) * w;
        }
    }

    const float4 b4 = *(const float4*)(bias + (lane << 2));
    float4 r;
    r.x = acc.x + b4.x;
    r.y = acc.y + b4.y;
    r.z = acc.z + b4.z;
    r.w = acc.w + b4.w;
    r.x = r.x > 0.f ? r.x : __expf(r.x) - 1.f;
    r.y = r.y > 0.f ? r.y : __expf(r.y) - 1.f;
    r.z = r.z > 0.f ? r.z : __expf(r.z) - 1.f;
    r.w = r.w > 0.f ? r.w : __expf(r.w) - 1.f;
    ushort4 o4;
    o4.x = f2b(r.x); o4.y = f2b(r.y); o4.z = f2b(r.z); o4.w = f2b(r.w);
    *(ushort4*)(featb + (size_t)v * HDIM + (lane << 2)) = o4;
}

// ---- final linear [256->40] + log_softmax (bf16 features), class dim padded to 64 ----
__global__ __launch_bounds__(256) void final_kernel(const unsigned short* __restrict__ featb,
                                                    const float* __restrict__ Wl,
                                                    const float* __restrict__ bl,
                                                    float* __restrict__ out) {
    const int BK = 16;
    __shared__ float As[BK][65];
    __shared__ float Bs[BK][65];
    int tx = threadIdx.x & 15, ty = threadIdx.x >> 4;
    int row0 = blockIdx.x * 64;
    float acc[4][4] = {};
    for (int k0 = 0; k0 < HDIM; k0 += BK) {
#pragma unroll
        for (int i = 0; i < 4; i++) {
            int l = threadIdx.x + 256 * i;
            int r = l >> 4, c = l & 15;
            int gr = row0 + r;
            float v = 0.f;
            if (gr < NN) v = b2f(featb[(size_t)gr * HDIM + k0 + c]);
            As[c][r] = v;
        }
#pragma unroll
        for (int i = 0; i < 4; i++) {
            int l = threadIdx.x + 256 * i;
            int r = l >> 6, c = l & 63;
            Bs[r][c] = (c < NCLS) ? Wl[(size_t)(k0 + r) * NCLS + c] : 0.f;
        }
        __syncthreads();
#pragma unroll
        for (int k = 0; k < BK; k++) {
            float a[4], b[4];
#pragma unroll
            for (int i = 0; i < 4; i++) a[i] = As[k][ty + 16 * i];
#pragma unroll
            for (int j = 0; j < 4; j++) b[j] = Bs[k][tx + 16 * j];
#pragma unroll
            for (int i = 0; i < 4; i++)
#pragma unroll
                for (int j = 0; j < 4; j++) acc[i][j] += a[i] * b[j];
        }
        __syncthreads();
    }
    float b0 = bl[tx], b1 = bl[tx + 16], b2 = (tx < 8) ? bl[tx + 32] : 0.f;
#pragma unroll
    for (int i = 0; i < 4; i++) {
        int gr = row0 + ty + 16 * i;
        if (gr >= NN) continue;
        float l0 = acc[i][0] + b0;
        float l1 = acc[i][1] + b1;
        float l2 = (tx < 8) ? acc[i][2] + b2 : -INFINITY;
        float m = fmaxf(fmaxf(l0, l1), l2);
#pragma unroll
        for (int o = 8; o > 0; o >>= 1) m = fmaxf(m, __shfl_xor(m, o));
        float s = __expf(l0 - m) + __expf(l1 - m) + ((tx < 8) ? __expf(l2 - m) : 0.f);
#pragma unroll
        for (int o = 8; o > 0; o >>= 1) s += __shfl_xor(s, o);
        float lse = m + __logf(s);
        out[(size_t)gr * NCLS + tx] = l0 - lse;
        out[(size_t)gr * NCLS + tx + 16] = l1 - lse;
        if (tx < 8) out[(size_t)gr * NCLS + tx + 32] = l2 - lse;
    }
}

extern "C" void kernel_launch(void* const* d_in, const int* in_sizes, int n_in,
                              void* d_out, int out_size, void* d_ws, size_t ws_size,
                              hipStream_t stream) {
    const float* x  = (const float*)d_in[0];
    const int* ei32 = (const int*)d_in[1];
    const float* W1 = (const float*)d_in[2];
    const float* as1 = (const float*)d_in[3];
    const float* ad1 = (const float*)d_in[4];
    const float* b1 = (const float*)d_in[5];
    const float* W2 = (const float*)d_in[6];
    const float* as2 = (const float*)d_in[7];
    const float* ad2 = (const float*)d_in[8];
    const float* b2 = (const float*)d_in[9];
    const float* W3 = (const float*)d_in[10];
    const float* as3 = (const float*)d_in[11];
    const float* ad3 = (const float*)d_in[12];
    const float* b3 = (const float*)d_in[13];
    const float* Wl = (const float*)d_in[14];
    const float* bl = (const float*)d_in[15];
    float* out = (float*)d_out;

    // workspace layout
    char* w = (char*)d_ws;
    unsigned short* projb = (unsigned short*)w;  w += (size_t)NN * HDIM * 2;
    unsigned short* featb = (unsigned short*)w;  w += (size_t)NN * HDIM * 2;
    unsigned short* xb    = (unsigned short*)w;  w += (size_t)NN * FIN * 2;
    unsigned short* Wt1b  = (unsigned short*)w;  w += (size_t)HDIM * FIN * 2;
    unsigned short* Wt2b  = (unsigned short*)w;  w += (size_t)HDIM * HDIM * 2;
    unsigned short* Wt3b  = (unsigned short*)w;  w += (size_t)HDIM * HDIM * 2;
    float* als  = (float*)w;  w += (size_t)NN * NHEAD * 4;
    float* ald  = (float*)w;  w += (size_t)NN * NHEAD * 4;
    int* deg    = (int*)w;    w += (size_t)NN * 4;
    int* incl   = (int*)w;    w += (size_t)NN * 4;
    int* bsum   = (int*)w;    w += 256 * 4;
    int* indptr = (int*)w;    w += (size_t)(NN + 1) * 4;
    int* cursor = (int*)w;    w += (size_t)NN * 4;
    int* esrc   = (int*)w;    w += (size_t)ET * 4;
    int* flag   = (int*)w;    w += 64;

    // ---- one-time conversions ----
    conv_kernel<<<(NN * FIN / 8 + 255) / 256, 256, 0, stream>>>(x, xb, NN * FIN);
    wconv_kernel<<<dim3(8, FIN / 32), 256, 0, stream>>>(W1, Wt1b, FIN);
    wconv_kernel<<<dim3(8, HDIM / 32), 256, 0, stream>>>(W2, Wt2b, HDIM);
    wconv_kernel<<<dim3(8, HDIM / 32), 256, 0, stream>>>(W3, Wt3b, HDIM);

    // ---- CSR build (same edge structure for all three layers) ----
    hipMemsetAsync(deg, 0, (size_t)NN * 4, stream);
    detect_kernel<<<1, 64, 0, stream>>>(ei32, flag);
    deg_kernel<<<(ET + 255) / 256, 256, 0, stream>>>(ei32, flag, deg);
    scan1<<<NB_SCAN, 256, 0, stream>>>(deg, incl, bsum);
    scan2<<<1, 256, 0, stream>>>(bsum);
    scan3<<<NB_SCAN, 256, 0, stream>>>(incl, bsum, deg, indptr, cursor);
    fill_kernel<<<(ET + 255) / 256, 256, 0, stream>>>(ei32, flag, cursor, esrc);

    dim3 ggrid(HDIM / 64, (NN + 127) / 128);
    int agrid = (NN + 3) / 4;

    // ---- layer 1 ----
    gemm_mfma<<<ggrid, 256, 0, stream>>>(xb, Wt1b, projb, as1, ad1, als, ald, NN, FIN);
    agg_kernel<<<agrid, 256, 0, stream>>>(projb, als, ald, indptr, esrc, b1, featb);
    // ---- layer 2 ----
    gemm_mfma<<<ggrid, 256, 0, stream>>>(featb, Wt2b, projb, as2, ad2, als, ald, NN, HDIM);
    agg_kernel<<<agrid, 256, 0, stream>>>(projb, als, ald, indptr, esrc, b2, featb);
    // ---- layer 3 ----
    gemm_mfma<<<ggrid, 256, 0, stream>>>(featb, Wt3b, projb, as3, ad3, als, ald, NN, HDIM);
    agg_kernel<<<agrid, 256, 0, stream>>>(projb, als, ald, indptr, esrc, b3, featb);
    // ---- final linear + log_softmax (fused) ----
    final_kernel<<<(NN + 63) / 64, 256, 0, stream>>>(featb, Wl, bl, out);
}

// Round 7
// 479.094 us; speedup vs baseline: 4.1727x; 1.0195x over previous
//
#include <hip/hip_runtime.h>
#include <math.h>

#define NN 50000
#define NE 800000
#define ET (NE + NN)          // edges + self loops = 850000
#define FIN 128
#define HDIM 256
#define NHEAD 4
#define NCLS 40
#define NEG 0.2f
#define NB_SCAN ((NN + 255) / 256)   // 196

typedef short bf16x8 __attribute__((ext_vector_type(8)));
typedef float f32x4 __attribute__((ext_vector_type(4)));

__device__ __forceinline__ unsigned short f2b(float f) {
    unsigned int u = __float_as_uint(f);
    unsigned int r = (u + 0x7fffu + ((u >> 16) & 1u)) >> 16;
    return (unsigned short)r;
}
__device__ __forceinline__ float b2f(unsigned short u) {
    unsigned int x = ((unsigned int)u) << 16;
    return __uint_as_float(x);
}

// ---------------- edge-index dtype sniff (int64 vs int32) ----------------
__global__ void detect_kernel(const int* __restrict__ ei32, int* __restrict__ flag) {
    if (threadIdx.x == 0 && blockIdx.x == 0) {
        int is64 = 1;
        for (int i = 1; i < 256; i += 2)
            if (ei32[i] != 0) { is64 = 0; break; }
        *flag = is64;
    }
}

__device__ __forceinline__ int load_node(const int* ei32, int is64, long long idx) {
    return is64 ? ei32[2 * idx] : ei32[idx];
}

// ---------------- CSR build ----------------
__global__ void deg_kernel(const int* __restrict__ ei32, const int* __restrict__ flag,
                           int* __restrict__ deg) {
    int e = blockIdx.x * blockDim.x + threadIdx.x;
    if (e >= ET) return;
    int is64 = *flag;
    int d = (e < NE) ? load_node(ei32, is64, (long long)NE + e) : (e - NE);
    atomicAdd(&deg[d], 1);
}

__global__ void scan1(const int* __restrict__ deg, int* __restrict__ incl,
                      int* __restrict__ bsum) {
    __shared__ int sm[256];
    int i = blockIdx.x * 256 + threadIdx.x;
    int v = (i < NN) ? deg[i] : 0;
    sm[threadIdx.x] = v;
    __syncthreads();
    for (int o = 1; o < 256; o <<= 1) {
        int add = (threadIdx.x >= o) ? sm[threadIdx.x - o] : 0;
        __syncthreads();
        sm[threadIdx.x] += add;
        __syncthreads();
    }
    if (i < NN) incl[i] = sm[threadIdx.x];
    if (threadIdx.x == 255) bsum[blockIdx.x] = sm[255];
}

__global__ void scan2(int* __restrict__ bsum) {
    __shared__ int sm[256];
    int t = threadIdx.x;
    sm[t] = (t < NB_SCAN) ? bsum[t] : 0;
    __syncthreads();
    if (t == 0) {
        int run = 0;
        for (int b = 0; b < NB_SCAN; b++) { int v = sm[b]; sm[b] = run; run += v; }
    }
    __syncthreads();
    if (t < NB_SCAN) bsum[t] = sm[t];
}

__global__ void scan3(const int* __restrict__ incl, const int* __restrict__ bsum,
                      const int* __restrict__ deg, int* __restrict__ indptr,
                      int* __restrict__ cursor) {
    int i = blockIdx.x * 256 + threadIdx.x;
    if (i < NN) {
        int v = bsum[blockIdx.x] + incl[i];
        indptr[i + 1] = v;
        cursor[i] = v - deg[i];
    }
    if (i == 0) indptr[0] = 0;
}

__global__ void fill_kernel(const int* __restrict__ ei32, const int* __restrict__ flag,
                            int* __restrict__ cursor, int* __restrict__ esrc) {
    int e = blockIdx.x * blockDim.x + threadIdx.x;
    if (e >= ET) return;
    int is64 = *flag;
    int s, d;
    if (e < NE) {
        s = load_node(ei32, is64, (long long)e);
        d = load_node(ei32, is64, (long long)NE + e);
    } else {
        s = d = e - NE;
    }
    int pos = atomicAdd(&cursor[d], 1);
    esrc[pos] = s;
}

// ---------------- f32 -> bf16 elementwise (n divisible by 8) ----------------
__global__ __launch_bounds__(256) void conv_kernel(const float* __restrict__ in,
                                                   unsigned short* __restrict__ out, int n) {
    int i = (blockIdx.x * 256 + threadIdx.x) * 8;
    if (i + 8 > n) return;
    float4 f0 = *(const float4*)(in + i);
    float4 f1 = *(const float4*)(in + i + 4);
    ushort4 a, b;
    a.x = f2b(f0.x); a.y = f2b(f0.y); a.z = f2b(f0.z); a.w = f2b(f0.w);
    b.x = f2b(f1.x); b.y = f2b(f1.y); b.z = f2b(f1.z); b.w = f2b(f1.w);
    *(ushort4*)(out + i) = a;
    *(ushort4*)(out + i + 4) = b;
}

// ------- W[K][256] f32 -> Wt[256][K] bf16 (transpose + convert) -------
__global__ __launch_bounds__(256) void wconv_kernel(const float* __restrict__ W,
                                                    unsigned short* __restrict__ Wt, int K) {
    __shared__ float sm[32][33];
    int tx = threadIdx.x & 31, ty = threadIdx.x >> 5;   // 32 x 8
    int n0 = blockIdx.x * 32, k0 = blockIdx.y * 32;
#pragma unroll
    for (int j = 0; j < 4; j++)
        sm[ty + j * 8][tx] = W[(size_t)(k0 + ty + j * 8) * HDIM + n0 + tx];
    __syncthreads();
#pragma unroll
    for (int j = 0; j < 4; j++)
        Wt[(size_t)(n0 + ty + j * 8) * K + k0 + tx] = f2b(sm[tx][ty + j * 8]);
}

// ------- MFMA GEMM + fused alpha: Cb[M,256](bf16) = A*Bt^T; als/ald per (row, head) -------
__global__ __launch_bounds__(256) void gemm_mfma(const unsigned short* __restrict__ A,
                                                 const unsigned short* __restrict__ Bt,
                                                 unsigned short* __restrict__ Cb,
                                                 const float* __restrict__ a_s,
                                                 const float* __restrict__ a_d,
                                                 float* __restrict__ als,
                                                 float* __restrict__ ald,
                                                 int M, int K) {
    __shared__ unsigned short As[128][72];   // stride 144 B -> 2-way bank alias (free)
    __shared__ unsigned short Bs[64][72];
    int t = threadIdx.x;
    int lane = t & 63, wid = t >> 6;
    int r0 = blockIdx.y * 128, n0 = blockIdx.x * 64;

    f32x4 acc[2][4];
#pragma unroll
    for (int m = 0; m < 2; m++)
#pragma unroll
        for (int n = 0; n < 4; n++)
            acc[m][n] = (f32x4){0.f, 0.f, 0.f, 0.f};

    int ar = t >> 1, ah = (t & 1) * 32;
    int arow = r0 + ar; if (arow > M - 1) arow = M - 1;
    const unsigned short* ga = A + (size_t)arow * K + ah;
    int bn = t >> 2, bq = (t & 3) * 16;
    const unsigned short* gb = Bt + (size_t)(n0 + bn) * K + bq;

    int fr = lane & 15;          // frag row/col within 16
    int kf = (lane >> 4) * 8;    // k-octet

    for (int k0 = 0; k0 < K; k0 += 64) {
#pragma unroll
        for (int j = 0; j < 4; j++)
            *(uint4*)&As[ar][ah + j * 8] = *(const uint4*)(ga + k0 + j * 8);
#pragma unroll
        for (int j = 0; j < 2; j++)
            *(uint4*)&Bs[bn][bq + j * 8] = *(const uint4*)(gb + k0 + j * 8);
        __syncthreads();
#pragma unroll
        for (int kk = 0; kk < 64; kk += 32) {
            bf16x8 a[2], b[4];
#pragma unroll
            for (int m = 0; m < 2; m++)
                a[m] = *(const bf16x8*)&As[wid * 32 + m * 16 + fr][kk + kf];
#pragma unroll
            for (int n = 0; n < 4; n++)
                b[n] = *(const bf16x8*)&Bs[n * 16 + fr][kk + kf];
#pragma unroll
            for (int m = 0; m < 2; m++)
#pragma unroll
                for (int n = 0; n < 4; n++)
                    acc[m][n] = __builtin_amdgcn_mfma_f32_16x16x32_bf16(a[m], b[n], acc[m][n], 0, 0, 0);
        }
        __syncthreads();
    }

    int rbase = r0 + wid * 32 + (lane >> 4) * 4;
    int cbase = n0 + fr;
    int head = n0 >> 6;
    float asv[4], adv[4];
#pragma unroll
    for (int n = 0; n < 4; n++) {
        asv[n] = a_s[cbase + n * 16];
        adv[n] = a_d[cbase + n * 16];
    }
#pragma unroll
    for (int m = 0; m < 2; m++)
#pragma unroll
        for (int q = 0; q < 4; q++) {
            int gr = rbase + m * 16 + q;
            float vs = 0.f, vd = 0.f;
#pragma unroll
            for (int n = 0; n < 4; n++) {
                float v = acc[m][n][q];
                vs += v * asv[n];
                vd += v * adv[n];
                if (gr < M) Cb[(size_t)gr * HDIM + cbase + n * 16] = f2b(v);
            }
#pragma unroll
            for (int o = 8; o > 0; o >>= 1) {
                vs += __shfl_xor(vs, o);
                vd += __shfl_xor(vd, o);
            }
            if (fr == 0 && gr < M) {
                als[gr * NHEAD + head] = vs;
                ald[gr * NHEAD + head] = vd;
            }
        }
}

// ---- agg: one WAVE per node, bf16 gather, 16-deep batched loads for MLP ----
__global__ __launch_bounds__(256) void agg_kernel(const unsigned short* __restrict__ projb,
                                                  const float* __restrict__ als,
                                                  const float* __restrict__ ald,
                                                  const int* __restrict__ indptr,
                                                  const int* __restrict__ esrc,
                                                  const float* __restrict__ bias,
                                                  unsigned short* __restrict__ featb) {
    int wid = threadIdx.x >> 6;
    int v = blockIdx.x * 4 + wid;
    if (v >= NN) return;
    int lane = threadIdx.x & 63;
    int h = lane >> 4;
    int sub = lane & 15;
    int beg = indptr[v], end = indptr[v + 1];
    float adv = ald[v * NHEAD + h];

    float m = -INFINITY, ss = 0.f;
    for (int i = beg + sub; i < end; i += 16) {
        int s = esrc[i];
        float e = als[s * NHEAD + h] + adv;
        e = e > 0.f ? e : NEG * e;
        if (e > m) {
            ss = ss * __expf(m - e) + 1.f;
            m = e;
        } else {
            ss += __expf(e - m);
        }
    }
#pragma unroll
    for (int o = 8; o > 0; o >>= 1) {
        float m2 = __shfl_xor(m, o);
        float s2 = __shfl_xor(ss, o);
        float mn = fmaxf(m, m2);
        float a = (m == mn) ? ss : ss * __expf(m - mn);
        float b = (m2 == mn) ? s2 : s2 * __expf(m2 - mn);
        m = mn;
        ss = a + b;
    }
    float inv = 1.f / (ss + 1e-16f);

    float4 acc = make_float4(0.f, 0.f, 0.f, 0.f);
    int c = beg;
    // ---- full chunks: batch 16 independent gathers, then FMA ----
    for (; c + 16 <= end; c += 16) {
        int sreg = esrc[c + sub];
        float e = als[sreg * NHEAD + h] + adv;
        e = e > 0.f ? e : NEG * e;
        float wreg = __expf(e - m) * inv;

        ushort4 p[16];
#pragma unroll
        for (int j = 0; j < 16; j++) {
            int s = __shfl(sreg, j);
            p[j] = *(const ushort4*)(projb + (size_t)s * HDIM + (lane << 2));
        }
#pragma unroll
        for (int j = 0; j < 16; j++) {
            float w = __shfl(wreg, (h << 4) | j);
            acc.x += b2f(p[j].x) * w;
            acc.y += b2f(p[j].y) * w;
            acc.z += b2f(p[j].z) * w;
            acc.w += b2f(p[j].w) * w;
        }
    }
    // ---- ragged tail ----
    int n = end - c;
    if (n > 0) {
        float wreg = 0.f;
        int sreg = 0;
        if (sub < n) {
            sreg = esrc[c + sub];
            float e = als[sreg * NHEAD + h] + adv;
            e = e > 0.f ? e : NEG * e;
            wreg = __expf(e - m) * inv;
        }
        for (int j = 0; j < n; j++) {
            float w = __shfl(wreg, (h << 4) | j);
            int s = __shfl(sreg, j);
            const ushort4 p = *(const ushort4*)(projb + (size_t)s * HDIM + (lane << 2));
            acc.x += b2f(p.x) * w;
            acc.y += b2f(p.y) * w;
            acc.z += b2f(p.z) * w;
            acc.w += b2f(p.w) * w;
        }
    }

    const float4 b4 = *(const float4*)(bias + (lane << 2));
    float4 r;
    r.x = acc.x + b4.x;
    r.y = acc.y + b4.y;
    r.z = acc.z + b4.z;
    r.w = acc.w + b4.w;
    r.x = r.x > 0.f ? r.x : __expf(r.x) - 1.f;
    r.y = r.y > 0.f ? r.y : __expf(r.y) - 1.f;
    r.z = r.z > 0.f ? r.z : __expf(r.z) - 1.f;
    r.w = r.w > 0.f ? r.w : __expf(r.w) - 1.f;
    ushort4 o4;
    o4.x = f2b(r.x); o4.y = f2b(r.y); o4.z = f2b(r.z); o4.w = f2b(r.w);
    *(ushort4*)(featb + (size_t)v * HDIM + (lane << 2)) = o4;
}

// ---- final linear [256->40] + log_softmax (bf16 features), class dim padded to 64 ----
__global__ __launch_bounds__(256) void final_kernel(const unsigned short* __restrict__ featb,
                                                    const float* __restrict__ Wl,
                                                    const float* __restrict__ bl,
                                                    float* __restrict__ out) {
    const int BK = 16;
    __shared__ float As[BK][65];
    __shared__ float Bs[BK][65];
    int tx = threadIdx.x & 15, ty = threadIdx.x >> 4;
    int row0 = blockIdx.x * 64;
    float acc[4][4] = {};
    for (int k0 = 0; k0 < HDIM; k0 += BK) {
#pragma unroll
        for (int i = 0; i < 4; i++) {
            int l = threadIdx.x + 256 * i;
            int r = l >> 4, c = l & 15;
            int gr = row0 + r;
            float v = 0.f;
            if (gr < NN) v = b2f(featb[(size_t)gr * HDIM + k0 + c]);
            As[c][r] = v;
        }
#pragma unroll
        for (int i = 0; i < 4; i++) {
            int l = threadIdx.x + 256 * i;
            int r = l >> 6, c = l & 63;
            Bs[r][c] = (c < NCLS) ? Wl[(size_t)(k0 + r) * NCLS + c] : 0.f;
        }
        __syncthreads();
#pragma unroll
        for (int k = 0; k < BK; k++) {
            float a[4], b[4];
#pragma unroll
            for (int i = 0; i < 4; i++) a[i] = As[k][ty + 16 * i];
#pragma unroll
            for (int j = 0; j < 4; j++) b[j] = Bs[k][tx + 16 * j];
#pragma unroll
            for (int i = 0; i < 4; i++)
#pragma unroll
                for (int j = 0; j < 4; j++) acc[i][j] += a[i] * b[j];
        }
        __syncthreads();
    }
    float b0 = bl[tx], b1 = bl[tx + 16], b2 = (tx < 8) ? bl[tx + 32] : 0.f;
#pragma unroll
    for (int i = 0; i < 4; i++) {
        int gr = row0 + ty + 16 * i;
        if (gr >= NN) continue;
        float l0 = acc[i][0] + b0;
        float l1 = acc[i][1] + b1;
        float l2 = (tx < 8) ? acc[i][2] + b2 : -INFINITY;
        float m = fmaxf(fmaxf(l0, l1), l2);
#pragma unroll
        for (int o = 8; o > 0; o >>= 1) m = fmaxf(m, __shfl_xor(m, o));
        float s = __expf(l0 - m) + __expf(l1 - m) + ((tx < 8) ? __expf(l2 - m) : 0.f);
#pragma unroll
        for (int o = 8; o > 0; o >>= 1) s += __shfl_xor(s, o);
        float lse = m + __logf(s);
        out[(size_t)gr * NCLS + tx] = l0 - lse;
        out[(size_t)gr * NCLS + tx + 16] = l1 - lse;
        if (tx < 8) out[(size_t)gr * NCLS + tx + 32] = l2 - lse;
    }
}

extern "C" void kernel_launch(void* const* d_in, const int* in_sizes, int n_in,
                              void* d_out, int out_size, void* d_ws, size_t ws_size,
                              hipStream_t stream) {
    const float* x  = (const float*)d_in[0];
    const int* ei32 = (const int*)d_in[1];
    const float* W1 = (const float*)d_in[2];
    const float* as1 = (const float*)d_in[3];
    const float* ad1 = (const float*)d_in[4];
    const float* b1 = (const float*)d_in[5];
    const float* W2 = (const float*)d_in[6];
    const float* as2 = (const float*)d_in[7];
    const float* ad2 = (const float*)d_in[8];
    const float* b2 = (const float*)d_in[9];
    const float* W3 = (const float*)d_in[10];
    const float* as3 = (const float*)d_in[11];
    const float* ad3 = (const float*)d_in[12];
    const float* b3 = (const float*)d_in[13];
    const float* Wl = (const float*)d_in[14];
    const float* bl = (const float*)d_in[15];
    float* out = (float*)d_out;

    // workspace layout
    char* w = (char*)d_ws;
    unsigned short* projb = (unsigned short*)w;  w += (size_t)NN * HDIM * 2;
    unsigned short* featb = (unsigned short*)w;  w += (size_t)NN * HDIM * 2;
    unsigned short* xb    = (unsigned short*)w;  w += (size_t)NN * FIN * 2;
    unsigned short* Wt1b  = (unsigned short*)w;  w += (size_t)HDIM * FIN * 2;
    unsigned short* Wt2b  = (unsigned short*)w;  w += (size_t)HDIM * HDIM * 2;
    unsigned short* Wt3b  = (unsigned short*)w;  w += (size_t)HDIM * HDIM * 2;
    float* als  = (float*)w;  w += (size_t)NN * NHEAD * 4;
    float* ald  = (float*)w;  w += (size_t)NN * NHEAD * 4;
    int* deg    = (int*)w;    w += (size_t)NN * 4;
    int* incl   = (int*)w;    w += (size_t)NN * 4;
    int* bsum   = (int*)w;    w += 256 * 4;
    int* indptr = (int*)w;    w += (size_t)(NN + 1) * 4;
    int* cursor = (int*)w;    w += (size_t)NN * 4;
    int* esrc   = (int*)w;    w += (size_t)ET * 4;
    int* flag   = (int*)w;    w += 64;

    // ---- one-time conversions ----
    conv_kernel<<<(NN * FIN / 8 + 255) / 256, 256, 0, stream>>>(x, xb, NN * FIN);
    wconv_kernel<<<dim3(8, FIN / 32), 256, 0, stream>>>(W1, Wt1b, FIN);
    wconv_kernel<<<dim3(8, HDIM / 32), 256, 0, stream>>>(W2, Wt2b, HDIM);
    wconv_kernel<<<dim3(8, HDIM / 32), 256, 0, stream>>>(W3, Wt3b, HDIM);

    // ---- CSR build (same edge structure for all three layers) ----
    hipMemsetAsync(deg, 0, (size_t)NN * 4, stream);
    detect_kernel<<<1, 64, 0, stream>>>(ei32, flag);
    deg_kernel<<<(ET + 255) / 256, 256, 0, stream>>>(ei32, flag, deg);
    scan1<<<NB_SCAN, 256, 0, stream>>>(deg, incl, bsum);
    scan2<<<1, 256, 0, stream>>>(bsum);
    scan3<<<NB_SCAN, 256, 0, stream>>>(incl, bsum, deg, indptr, cursor);
    fill_kernel<<<(ET + 255) / 256, 256, 0, stream>>>(ei32, flag, cursor, esrc);

    dim3 ggrid(HDIM / 64, (NN + 127) / 128);
    int agrid = (NN + 3) / 4;

    // ---- layer 1 ----
    gemm_mfma<<<ggrid, 256, 0, stream>>>(xb, Wt1b, projb, as1, ad1, als, ald, NN, FIN);
    agg_kernel<<<agrid, 256, 0, stream>>>(projb, als, ald, indptr, esrc, b1, featb);
    // ---- layer 2 ----
    gemm_mfma<<<ggrid, 256, 0, stream>>>(featb, Wt2b, projb, as2, ad2, als, ald, NN, HDIM);
    agg_kernel<<<agrid, 256, 0, stream>>>(projb, als, ald, indptr, esrc, b2, featb);
    // ---- layer 3 ----
    gemm_mfma<<<ggrid, 256, 0, stream>>>(featb, Wt3b, projb, as3, ad3, als, ald, NN, HDIM);
    agg_kernel<<<agrid, 256, 0, stream>>>(projb, als, ald, indptr, esrc, b3, featb);
    // ---- final linear + log_softmax (fused) ----
    final_kernel<<<(NN + 63) / 64, 256, 0, stream>>>(featb, Wl, bl, out);
}

// Round 8
// 451.514 us; speedup vs baseline: 4.4276x; 1.0611x over previous
//
#include <hip/hip_runtime.h>
#include <math.h>

#define NN 50000
#define NE 800000
#define ET (NE + NN)          // edges + self loops = 850000
#define FIN 128
#define HDIM 256
#define NHEAD 4
#define NCLS 40
#define NEG 0.2f
#define NB_SCAN ((NN + 255) / 256)   // 196

typedef short bf16x8 __attribute__((ext_vector_type(8)));
typedef float f32x4 __attribute__((ext_vector_type(4)));

__device__ __forceinline__ unsigned short f2b(float f) {
    unsigned int u = __float_as_uint(f);
    unsigned int r = (u + 0x7fffu + ((u >> 16) & 1u)) >> 16;
    return (unsigned short)r;
}
__device__ __forceinline__ float b2f(unsigned short u) {
    unsigned int x = ((unsigned int)u) << 16;
    return __uint_as_float(x);
}

// ---------------- edge-index dtype sniff (int64 vs int32) ----------------
__global__ void detect_kernel(const int* __restrict__ ei32, int* __restrict__ flag) {
    if (threadIdx.x == 0 && blockIdx.x == 0) {
        int is64 = 1;
        for (int i = 1; i < 256; i += 2)
            if (ei32[i] != 0) { is64 = 0; break; }
        *flag = is64;
    }
}

__device__ __forceinline__ int load_node(const int* ei32, int is64, long long idx) {
    return is64 ? ei32[2 * idx] : ei32[idx];
}

// ---------------- CSR build ----------------
__global__ void deg_kernel(const int* __restrict__ ei32, const int* __restrict__ flag,
                           int* __restrict__ deg) {
    int e = blockIdx.x * blockDim.x + threadIdx.x;
    if (e >= ET) return;
    int is64 = *flag;
    int d = (e < NE) ? load_node(ei32, is64, (long long)NE + e) : (e - NE);
    atomicAdd(&deg[d], 1);
}

__global__ void scan1(const int* __restrict__ deg, int* __restrict__ incl,
                      int* __restrict__ bsum) {
    __shared__ int sm[256];
    int i = blockIdx.x * 256 + threadIdx.x;
    int v = (i < NN) ? deg[i] : 0;
    sm[threadIdx.x] = v;
    __syncthreads();
    for (int o = 1; o < 256; o <<= 1) {
        int add = (threadIdx.x >= o) ? sm[threadIdx.x - o] : 0;
        __syncthreads();
        sm[threadIdx.x] += add;
        __syncthreads();
    }
    if (i < NN) incl[i] = sm[threadIdx.x];
    if (threadIdx.x == 255) bsum[blockIdx.x] = sm[255];
}

__global__ void scan2(int* __restrict__ bsum) {
    __shared__ int sm[256];
    int t = threadIdx.x;
    sm[t] = (t < NB_SCAN) ? bsum[t] : 0;
    __syncthreads();
    if (t == 0) {
        int run = 0;
        for (int b = 0; b < NB_SCAN; b++) { int v = sm[b]; sm[b] = run; run += v; }
    }
    __syncthreads();
    if (t < NB_SCAN) bsum[t] = sm[t];
}

__global__ void scan3(const int* __restrict__ incl, const int* __restrict__ bsum,
                      const int* __restrict__ deg, int* __restrict__ indptr,
                      int* __restrict__ cursor) {
    int i = blockIdx.x * 256 + threadIdx.x;
    if (i < NN) {
        int v = bsum[blockIdx.x] + incl[i];
        indptr[i + 1] = v;
        cursor[i] = v - deg[i];
    }
    if (i == 0) indptr[0] = 0;
}

__global__ void fill_kernel(const int* __restrict__ ei32, const int* __restrict__ flag,
                            int* __restrict__ cursor, int* __restrict__ esrc) {
    int e = blockIdx.x * blockDim.x + threadIdx.x;
    if (e >= ET) return;
    int is64 = *flag;
    int s, d;
    if (e < NE) {
        s = load_node(ei32, is64, (long long)e);
        d = load_node(ei32, is64, (long long)NE + e);
    } else {
        s = d = e - NE;
    }
    int pos = atomicAdd(&cursor[d], 1);
    esrc[pos] = s;
}

// ------- W[K][256] f32 -> Wt[256][K] bf16 (transpose + convert) -------
__global__ __launch_bounds__(256) void wconv_kernel(const float* __restrict__ W,
                                                    unsigned short* __restrict__ Wt, int K) {
    __shared__ float sm[32][33];
    int tx = threadIdx.x & 31, ty = threadIdx.x >> 5;   // 32 x 8
    int n0 = blockIdx.x * 32, k0 = blockIdx.y * 32;
#pragma unroll
    for (int j = 0; j < 4; j++)
        sm[ty + j * 8][tx] = W[(size_t)(k0 + ty + j * 8) * HDIM + n0 + tx];
    __syncthreads();
#pragma unroll
    for (int j = 0; j < 4; j++)
        Wt[(size_t)(n0 + ty + j * 8) * K + k0 + tx] = f2b(sm[tx][ty + j * 8]);
}

// ------- MFMA GEMM + fused alpha; A either bf16 or f32 (A32 != nullptr) -------
// C written bf16 via LDS bounce (coalesced); als/ald per (row, head) fused.
__global__ __launch_bounds__(256) void gemm_mfma(const unsigned short* __restrict__ A,
                                                 const float* __restrict__ A32,
                                                 const unsigned short* __restrict__ Bt,
                                                 unsigned short* __restrict__ Cb,
                                                 const float* __restrict__ a_s,
                                                 const float* __restrict__ a_d,
                                                 float* __restrict__ als,
                                                 float* __restrict__ ald,
                                                 int M, int K) {
    __shared__ unsigned short As[128][72];   // stride 144 B -> 2-way bank alias (free)
    __shared__ unsigned short Bs[64][72];
    int t = threadIdx.x;
    int lane = t & 63, wid = t >> 6;
    int r0 = blockIdx.y * 128, n0 = blockIdx.x * 64;

    f32x4 acc[2][4];
#pragma unroll
    for (int m = 0; m < 2; m++)
#pragma unroll
        for (int n = 0; n < 4; n++)
            acc[m][n] = (f32x4){0.f, 0.f, 0.f, 0.f};

    int ar = t >> 1, ah = (t & 1) * 32;
    int arow = r0 + ar; if (arow > M - 1) arow = M - 1;
    const unsigned short* ga = A + (size_t)arow * K + ah;
    const float* ga32 = A32 ? (A32 + (size_t)arow * K + ah) : (const float*)0;
    int bn = t >> 2, bq = (t & 3) * 16;
    const unsigned short* gb = Bt + (size_t)(n0 + bn) * K + bq;

    int fr = lane & 15;          // frag row/col within 16
    int kf = (lane >> 4) * 8;    // k-octet

    for (int k0 = 0; k0 < K; k0 += 64) {
        if (A32) {
#pragma unroll
            for (int j = 0; j < 4; j++) {
                float4 fa = *(const float4*)(ga32 + k0 + j * 8);
                float4 fb = *(const float4*)(ga32 + k0 + j * 8 + 4);
                union { ushort4 u[2]; uint4 v; } pk;
                pk.u[0].x = f2b(fa.x); pk.u[0].y = f2b(fa.y);
                pk.u[0].z = f2b(fa.z); pk.u[0].w = f2b(fa.w);
                pk.u[1].x = f2b(fb.x); pk.u[1].y = f2b(fb.y);
                pk.u[1].z = f2b(fb.z); pk.u[1].w = f2b(fb.w);
                *(uint4*)&As[ar][ah + j * 8] = pk.v;
            }
        } else {
#pragma unroll
            for (int j = 0; j < 4; j++)
                *(uint4*)&As[ar][ah + j * 8] = *(const uint4*)(ga + k0 + j * 8);
        }
#pragma unroll
        for (int j = 0; j < 2; j++)
            *(uint4*)&Bs[bn][bq + j * 8] = *(const uint4*)(gb + k0 + j * 8);
        __syncthreads();
#pragma unroll
        for (int kk = 0; kk < 64; kk += 32) {
            bf16x8 a[2], b[4];
#pragma unroll
            for (int m = 0; m < 2; m++)
                a[m] = *(const bf16x8*)&As[wid * 32 + m * 16 + fr][kk + kf];
#pragma unroll
            for (int n = 0; n < 4; n++)
                b[n] = *(const bf16x8*)&Bs[n * 16 + fr][kk + kf];
#pragma unroll
            for (int m = 0; m < 2; m++)
#pragma unroll
                for (int n = 0; n < 4; n++)
                    acc[m][n] = __builtin_amdgcn_mfma_f32_16x16x32_bf16(a[m], b[n], acc[m][n], 0, 0, 0);
        }
        __syncthreads();
    }

    // ---- fused alpha reduction (register-level, before LDS reuse) ----
    int rbase = r0 + wid * 32 + (lane >> 4) * 4;
    int cbase = n0 + fr;
    int head = n0 >> 6;
    float asv[4], adv[4];
#pragma unroll
    for (int n = 0; n < 4; n++) {
        asv[n] = a_s[cbase + n * 16];
        adv[n] = a_d[cbase + n * 16];
    }
#pragma unroll
    for (int m = 0; m < 2; m++)
#pragma unroll
        for (int q = 0; q < 4; q++) {
            int gr = rbase + m * 16 + q;
            float vs = 0.f, vd = 0.f;
#pragma unroll
            for (int n = 0; n < 4; n++) {
                float v = acc[m][n][q];
                vs += v * asv[n];
                vd += v * adv[n];
            }
#pragma unroll
            for (int o = 8; o > 0; o >>= 1) {
                vs += __shfl_xor(vs, o);
                vd += __shfl_xor(vd, o);
            }
            if (fr == 0 && gr < M) {
                als[gr * NHEAD + head] = vs;
                ald[gr * NHEAD + head] = vd;
            }
        }

    // ---- C store: LDS bounce (reuse As; [128][68] pad -> conflict-free) ----
    unsigned short (*Cs)[68] = (unsigned short(*)[68])&As[0][0];
    int lr0 = wid * 32 + (lane >> 4) * 4;
#pragma unroll
    for (int m = 0; m < 2; m++)
#pragma unroll
        for (int q = 0; q < 4; q++)
#pragma unroll
            for (int n = 0; n < 4; n++)
                Cs[lr0 + m * 16 + q][fr + n * 16] = f2b(acc[m][n][q]);
    __syncthreads();
    int tr = t >> 4;
    int tc = (t & 15) * 4;
#pragma unroll
    for (int rr = 0; rr < 8; rr++) {
        int lr = tr + rr * 16;
        int gr = r0 + lr;
        if (gr < M) *(ushort4*)(Cb + (size_t)gr * HDIM + n0 + tc) = *(const ushort4*)&Cs[lr][tc];
    }
}

// ---- agg: one WAVE per node; (src,e) of first 2 chunks cached in registers ----
__global__ __launch_bounds__(256) void agg_kernel(const unsigned short* __restrict__ projb,
                                                  const float* __restrict__ als,
                                                  const float* __restrict__ ald,
                                                  const int* __restrict__ indptr,
                                                  const int* __restrict__ esrc,
                                                  const float* __restrict__ bias,
                                                  unsigned short* __restrict__ featb) {
    int wid = threadIdx.x >> 6;
    int v = blockIdx.x * 4 + wid;
    if (v >= NN) return;
    int lane = threadIdx.x & 63;
    int h = lane >> 4;
    int sub = lane & 15;
    int beg = indptr[v], end = indptr[v + 1];
    float adv = ald[v * NHEAD + h];

    // ---- phase 1: online (max,sumexp); cache (s,e) for first 2 chunks ----
    float e0 = 0.f, e1 = 0.f;
    int s0r = 0, s1r = 0;
    float m = -INFINITY, ss = 0.f;
    int idx = 0;
    for (int i = beg + sub; i < end; i += 16, idx++) {
        int s = esrc[i];
        float e = als[s * NHEAD + h] + adv;
        e = e > 0.f ? e : NEG * e;
        if (idx == 0) { e0 = e; s0r = s; }
        else if (idx == 1) { e1 = e; s1r = s; }
        if (e > m) {
            ss = ss * __expf(m - e) + 1.f;
            m = e;
        } else {
            ss += __expf(e - m);
        }
    }
#pragma unroll
    for (int o = 8; o > 0; o >>= 1) {
        float m2 = __shfl_xor(m, o);
        float s2 = __shfl_xor(ss, o);
        float mn = fmaxf(m, m2);
        float a = (m == mn) ? ss : ss * __expf(m - mn);
        float b = (m2 == mn) ? s2 : s2 * __expf(m2 - mn);
        m = mn;
        ss = a + b;
    }
    float inv = 1.f / (ss + 1e-16f);

    float4 acc = make_float4(0.f, 0.f, 0.f, 0.f);
    int c = beg;
    int chunk = 0;
    // ---- full chunks: cached (s,e) for chunks 0/1 -> no leading loads ----
    for (; c + 16 <= end; c += 16, chunk++) {
        int sreg;
        float eC;
        if (chunk == 0) { sreg = s0r; eC = e0; }
        else if (chunk == 1) { sreg = s1r; eC = e1; }
        else {
            sreg = esrc[c + sub];
            eC = als[sreg * NHEAD + h] + adv;
            eC = eC > 0.f ? eC : NEG * eC;
        }
        float wreg = __expf(eC - m) * inv;

        ushort4 p[16];
#pragma unroll
        for (int j = 0; j < 16; j++) {
            int s = __shfl(sreg, j);
            p[j] = *(const ushort4*)(projb + (size_t)s * HDIM + (lane << 2));
        }
#pragma unroll
        for (int j = 0; j < 16; j++) {
            float w = __shfl(wreg, (h << 4) | j);
            acc.x += b2f(p[j].x) * w;
            acc.y += b2f(p[j].y) * w;
            acc.z += b2f(p[j].z) * w;
            acc.w += b2f(p[j].w) * w;
        }
    }
    // ---- ragged tail ----
    int n = end - c;
    if (n > 0) {
        int sreg;
        float eT;
        if (chunk == 0) { sreg = s0r; eT = e0; }
        else if (chunk == 1) { sreg = s1r; eT = e1; }
        else {
            sreg = (sub < n) ? esrc[c + sub] : 0;
            eT = als[sreg * NHEAD + h] + adv;
            eT = eT > 0.f ? eT : NEG * eT;
        }
        float wreg = (sub < n) ? __expf(eT - m) * inv : 0.f;
        for (int j = 0; j < n; j++) {
            float w = __shfl(wreg, (h << 4) | j);
            int s = __shfl(sreg, j);
            const ushort4 p = *(const ushort4*)(projb + (size_t)s * HDIM + (lane << 2));
            acc.x += b2f(p.x) * w;
            acc.y += b2f(p.y) * w;
            acc.z += b2f(p.z) * w;
            acc.w += b2f(p.w) * w;
        }
    }

    const float4 b4 = *(const float4*)(bias + (lane << 2));
    float4 r;
    r.x = acc.x + b4.x;
    r.y = acc.y + b4.y;
    r.z = acc.z + b4.z;
    r.w = acc.w + b4.w;
    r.x = r.x > 0.f ? r.x : __expf(r.x) - 1.f;
    r.y = r.y > 0.f ? r.y : __expf(r.y) - 1.f;
    r.z = r.z > 0.f ? r.z : __expf(r.z) - 1.f;
    r.w = r.w > 0.f ? r.w : __expf(r.w) - 1.f;
    ushort4 o4;
    o4.x = f2b(r.x); o4.y = f2b(r.y); o4.z = f2b(r.z); o4.w = f2b(r.w);
    *(ushort4*)(featb + (size_t)v * HDIM + (lane << 2)) = o4;
}

// ---- final linear [256->40] + log_softmax (bf16 features), class dim padded to 64 ----
__global__ __launch_bounds__(256) void final_kernel(const unsigned short* __restrict__ featb,
                                                    const float* __restrict__ Wl,
                                                    const float* __restrict__ bl,
                                                    float* __restrict__ out) {
    const int BK = 16;
    __shared__ float As[BK][65];
    __shared__ float Bs[BK][65];
    int tx = threadIdx.x & 15, ty = threadIdx.x >> 4;
    int row0 = blockIdx.x * 64;
    float acc[4][4] = {};
    for (int k0 = 0; k0 < HDIM; k0 += BK) {
#pragma unroll
        for (int i = 0; i < 4; i++) {
            int l = threadIdx.x + 256 * i;
            int r = l >> 4, c = l & 15;
            int gr = row0 + r;
            float v = 0.f;
            if (gr < NN) v = b2f(featb[(size_t)gr * HDIM + k0 + c]);
            As[c][r] = v;
        }
#pragma unroll
        for (int i = 0; i < 4; i++) {
            int l = threadIdx.x + 256 * i;
            int r = l >> 6, c = l & 63;
            Bs[r][c] = (c < NCLS) ? Wl[(size_t)(k0 + r) * NCLS + c] : 0.f;
        }
        __syncthreads();
#pragma unroll
        for (int k = 0; k < BK; k++) {
            float a[4], b[4];
#pragma unroll
            for (int i = 0; i < 4; i++) a[i] = As[k][ty + 16 * i];
#pragma unroll
            for (int j = 0; j < 4; j++) b[j] = Bs[k][tx + 16 * j];
#pragma unroll
            for (int i = 0; i < 4; i++)
#pragma unroll
                for (int j = 0; j < 4; j++) acc[i][j] += a[i] * b[j];
        }
        __syncthreads();
    }
    float b0 = bl[tx], b1 = bl[tx + 16], b2 = (tx < 8) ? bl[tx + 32] : 0.f;
#pragma unroll
    for (int i = 0; i < 4; i++) {
        int gr = row0 + ty + 16 * i;
        if (gr >= NN) continue;
        float l0 = acc[i][0] + b0;
        float l1 = acc[i][1] + b1;
        float l2 = (tx < 8) ? acc[i][2] + b2 : -INFINITY;
        float m = fmaxf(fmaxf(l0, l1), l2);
#pragma unroll
        for (int o = 8; o > 0; o >>= 1) m = fmaxf(m, __shfl_xor(m, o));
        float s = __expf(l0 - m) + __expf(l1 - m) + ((tx < 8) ? __expf(l2 - m) : 0.f);
#pragma unroll
        for (int o = 8; o > 0; o >>= 1) s += __shfl_xor(s, o);
        float lse = m + __logf(s);
        out[(size_t)gr * NCLS + tx] = l0 - lse;
        out[(size_t)gr * NCLS + tx + 16] = l1 - lse;
        if (tx < 8) out[(size_t)gr * NCLS + tx + 32] = l2 - lse;
    }
}

extern "C" void kernel_launch(void* const* d_in, const int* in_sizes, int n_in,
                              void* d_out, int out_size, void* d_ws, size_t ws_size,
                              hipStream_t stream) {
    const float* x  = (const float*)d_in[0];
    const int* ei32 = (const int*)d_in[1];
    const float* W1 = (const float*)d_in[2];
    const float* as1 = (const float*)d_in[3];
    const float* ad1 = (const float*)d_in[4];
    const float* b1 = (const float*)d_in[5];
    const float* W2 = (const float*)d_in[6];
    const float* as2 = (const float*)d_in[7];
    const float* ad2 = (const float*)d_in[8];
    const float* b2 = (const float*)d_in[9];
    const float* W3 = (const float*)d_in[10];
    const float* as3 = (const float*)d_in[11];
    const float* ad3 = (const float*)d_in[12];
    const float* b3 = (const float*)d_in[13];
    const float* Wl = (const float*)d_in[14];
    const float* bl = (const float*)d_in[15];
    float* out = (float*)d_out;

    // workspace layout
    char* w = (char*)d_ws;
    unsigned short* projb = (unsigned short*)w;  w += (size_t)NN * HDIM * 2;
    unsigned short* featb = (unsigned short*)w;  w += (size_t)NN * HDIM * 2;
    unsigned short* Wt1b  = (unsigned short*)w;  w += (size_t)HDIM * FIN * 2;
    unsigned short* Wt2b  = (unsigned short*)w;  w += (size_t)HDIM * HDIM * 2;
    unsigned short* Wt3b  = (unsigned short*)w;  w += (size_t)HDIM * HDIM * 2;
    float* als  = (float*)w;  w += (size_t)NN * NHEAD * 4;
    float* ald  = (float*)w;  w += (size_t)NN * NHEAD * 4;
    int* deg    = (int*)w;    w += (size_t)NN * 4;
    int* incl   = (int*)w;    w += (size_t)NN * 4;
    int* bsum   = (int*)w;    w += 256 * 4;
    int* indptr = (int*)w;    w += (size_t)(NN + 1) * 4;
    int* cursor = (int*)w;    w += (size_t)NN * 4;
    int* esrc   = (int*)w;    w += (size_t)ET * 4;
    int* flag   = (int*)w;    w += 64;

    // ---- one-time conversions (x conversion fused into layer-1 GEMM) ----
    wconv_kernel<<<dim3(8, FIN / 32), 256, 0, stream>>>(W1, Wt1b, FIN);
    wconv_kernel<<<dim3(8, HDIM / 32), 256, 0, stream>>>(W2, Wt2b, HDIM);
    wconv_kernel<<<dim3(8, HDIM / 32), 256, 0, stream>>>(W3, Wt3b, HDIM);

    // ---- CSR build (same edge structure for all three layers) ----
    hipMemsetAsync(deg, 0, (size_t)NN * 4, stream);
    detect_kernel<<<1, 64, 0, stream>>>(ei32, flag);
    deg_kernel<<<(ET + 255) / 256, 256, 0, stream>>>(ei32, flag, deg);
    scan1<<<NB_SCAN, 256, 0, stream>>>(deg, incl, bsum);
    scan2<<<1, 256, 0, stream>>>(bsum);
    scan3<<<NB_SCAN, 256, 0, stream>>>(incl, bsum, deg, indptr, cursor);
    fill_kernel<<<(ET + 255) / 256, 256, 0, stream>>>(ei32, flag, cursor, esrc);

    dim3 ggrid(HDIM / 64, (NN + 127) / 128);
    int agrid = (NN + 3) / 4;

    // ---- layer 1 (A = f32 x, converted in staging) ----
    gemm_mfma<<<ggrid, 256, 0, stream>>>((const unsigned short*)0, x, Wt1b, projb, as1, ad1, als, ald, NN, FIN);
    agg_kernel<<<agrid, 256, 0, stream>>>(projb, als, ald, indptr, esrc, b1, featb);
    // ---- layer 2 ----
    gemm_mfma<<<ggrid, 256, 0, stream>>>(featb, (const float*)0, Wt2b, projb, as2, ad2, als, ald, NN, HDIM);
    agg_kernel<<<agrid, 256, 0, stream>>>(projb, als, ald, indptr, esrc, b2, featb);
    // ---- layer 3 ----
    gemm_mfma<<<ggrid, 256, 0, stream>>>(featb, (const float*)0, Wt3b, projb, as3, ad3, als, ald, NN, HDIM);
    agg_kernel<<<agrid, 256, 0, stream>>>(projb, als, ald, indptr, esrc, b3, featb);
    // ---- final linear + log_softmax (fused) ----
    final_kernel<<<(NN + 63) / 64, 256, 0, stream>>>(featb, Wl, bl, out);
}

// Round 9
// 435.311 us; speedup vs baseline: 4.5924x; 1.0372x over previous
//
#include <hip/hip_runtime.h>
#include <math.h>

#define NN 50000
#define NE 800000
#define ET (NE + NN)          // edges + self loops = 850000
#define FIN 128
#define HDIM 256
#define NHEAD 4
#define NCLS 40
#define NEG 0.2f
#define NB_SCAN ((NN + 255) / 256)   // 196

typedef short bf16x8 __attribute__((ext_vector_type(8)));
typedef float f32x4 __attribute__((ext_vector_type(4)));

__device__ __forceinline__ unsigned short f2b(float f) {
    unsigned int u = __float_as_uint(f);
    unsigned int r = (u + 0x7fffu + ((u >> 16) & 1u)) >> 16;
    return (unsigned short)r;
}
__device__ __forceinline__ float b2f(unsigned short u) {
    unsigned int x = ((unsigned int)u) << 16;
    return __uint_as_float(x);
}

// ---------------- edge-index dtype sniff (int64 vs int32), wave-parallel ----------------
__global__ void detect_kernel(const int* __restrict__ ei32, int* __restrict__ flag) {
    int lane = threadIdx.x;
    int nz = ei32[1 + 2 * lane] | ei32[129 + 2 * lane];
    unsigned long long b = __ballot(nz != 0);
    if (lane == 0) *flag = (b == 0ull) ? 1 : 0;
}

__device__ __forceinline__ int load_node(const int* ei32, int is64, long long idx) {
    return is64 ? ei32[2 * idx] : ei32[idx];
}

// ---------------- CSR build ----------------
__global__ void deg_kernel(const int* __restrict__ ei32, const int* __restrict__ flag,
                           int* __restrict__ deg) {
    int e = blockIdx.x * blockDim.x + threadIdx.x;
    if (e >= ET) return;
    int is64 = *flag;
    int d = (e < NE) ? load_node(ei32, is64, (long long)NE + e) : (e - NE);
    atomicAdd(&deg[d], 1);
}

__global__ void scan1(const int* __restrict__ deg, int* __restrict__ incl,
                      int* __restrict__ bsum) {
    __shared__ int sm[256];
    int i = blockIdx.x * 256 + threadIdx.x;
    int v = (i < NN) ? deg[i] : 0;
    sm[threadIdx.x] = v;
    __syncthreads();
    for (int o = 1; o < 256; o <<= 1) {
        int add = (threadIdx.x >= o) ? sm[threadIdx.x - o] : 0;
        __syncthreads();
        sm[threadIdx.x] += add;
        __syncthreads();
    }
    if (i < NN) incl[i] = sm[threadIdx.x];
    if (threadIdx.x == 255) bsum[blockIdx.x] = sm[255];
}

__global__ void scan2(int* __restrict__ bsum) {
    __shared__ int sm[256];
    int t = threadIdx.x;
    sm[t] = (t < NB_SCAN) ? bsum[t] : 0;
    __syncthreads();
    if (t == 0) {
        int run = 0;
        for (int b = 0; b < NB_SCAN; b++) { int v = sm[b]; sm[b] = run; run += v; }
    }
    __syncthreads();
    if (t < NB_SCAN) bsum[t] = sm[t];
}

__global__ void scan3(const int* __restrict__ incl, const int* __restrict__ bsum,
                      const int* __restrict__ deg, int* __restrict__ indptr,
                      int* __restrict__ cursor) {
    int i = blockIdx.x * 256 + threadIdx.x;
    if (i < NN) {
        int v = bsum[blockIdx.x] + incl[i];
        indptr[i + 1] = v;
        cursor[i] = v - deg[i];
    }
    if (i == 0) indptr[0] = 0;
}

__global__ void fill_kernel(const int* __restrict__ ei32, const int* __restrict__ flag,
                            int* __restrict__ cursor, int* __restrict__ esrc) {
    int e = blockIdx.x * blockDim.x + threadIdx.x;
    if (e >= ET) return;
    int is64 = *flag;
    int s, d;
    if (e < NE) {
        s = load_node(ei32, is64, (long long)e);
        d = load_node(ei32, is64, (long long)NE + e);
    } else {
        s = d = e - NE;
    }
    int pos = atomicAdd(&cursor[d], 1);
    esrc[pos] = s;
}

// ------- batched W[K][256] f32 -> Wt[256][K] bf16 for all 3 layers (z = layer) -------
__global__ __launch_bounds__(256) void wconv3_kernel(const float* __restrict__ W1,
                                                     const float* __restrict__ W2,
                                                     const float* __restrict__ W3,
                                                     unsigned short* __restrict__ Wt1,
                                                     unsigned short* __restrict__ Wt2,
                                                     unsigned short* __restrict__ Wt3) {
    __shared__ float sm[32][33];
    int z = blockIdx.z;
    const float* W = (z == 0) ? W1 : (z == 1) ? W2 : W3;
    unsigned short* Wt = (z == 0) ? Wt1 : (z == 1) ? Wt2 : Wt3;
    int K = (z == 0) ? FIN : HDIM;
    int k0 = blockIdx.y * 32;
    if (k0 >= K) return;
    int tx = threadIdx.x & 31, ty = threadIdx.x >> 5;   // 32 x 8
    int n0 = blockIdx.x * 32;
#pragma unroll
    for (int j = 0; j < 4; j++)
        sm[ty + j * 8][tx] = W[(size_t)(k0 + ty + j * 8) * HDIM + n0 + tx];
    __syncthreads();
#pragma unroll
    for (int j = 0; j < 4; j++)
        Wt[(size_t)(n0 + ty + j * 8) * K + k0 + tx] = f2b(sm[tx][ty + j * 8]);
}

// ------- MFMA GEMM + fused alpha; A either bf16 or f32 (A32 != nullptr) -------
// 1D grid with XCD-aware swizzle: all 4 col-blocks of a row-panel share bid%8 -> same XCD.
__global__ __launch_bounds__(256) void gemm_mfma(const unsigned short* __restrict__ A,
                                                 const float* __restrict__ A32,
                                                 const unsigned short* __restrict__ Bt,
                                                 unsigned short* __restrict__ Cb,
                                                 const float* __restrict__ a_s,
                                                 const float* __restrict__ a_d,
                                                 float* __restrict__ als,
                                                 float* __restrict__ ald,
                                                 int M, int K) {
    __shared__ unsigned short As[128][72];   // stride 144 B -> 2-way bank alias (free)
    __shared__ unsigned short Bs[64][72];
    int bid = blockIdx.x;
    int xcd = bid & 7, g = bid >> 3;
    int cblk = g & 3, rg = g >> 2;
    int rblk = rg * 8 + xcd;
    int r0 = rblk * 128, n0 = cblk * 64;
    if (r0 >= M) return;

    int t = threadIdx.x;
    int lane = t & 63, wid = t >> 6;

    f32x4 acc[2][4];
#pragma unroll
    for (int m = 0; m < 2; m++)
#pragma unroll
        for (int n = 0; n < 4; n++)
            acc[m][n] = (f32x4){0.f, 0.f, 0.f, 0.f};

    int ar = t >> 1, ah = (t & 1) * 32;
    int arow = r0 + ar; if (arow > M - 1) arow = M - 1;
    const unsigned short* ga = A + (size_t)arow * K + ah;
    const float* ga32 = A32 ? (A32 + (size_t)arow * K + ah) : (const float*)0;
    int bn = t >> 2, bq = (t & 3) * 16;
    const unsigned short* gb = Bt + (size_t)(n0 + bn) * K + bq;

    int fr = lane & 15;          // frag row/col within 16
    int kf = (lane >> 4) * 8;    // k-octet

    for (int k0 = 0; k0 < K; k0 += 64) {
        if (A32) {
#pragma unroll
            for (int j = 0; j < 4; j++) {
                float4 fa = *(const float4*)(ga32 + k0 + j * 8);
                float4 fb = *(const float4*)(ga32 + k0 + j * 8 + 4);
                union { ushort4 u[2]; uint4 v; } pk;
                pk.u[0].x = f2b(fa.x); pk.u[0].y = f2b(fa.y);
                pk.u[0].z = f2b(fa.z); pk.u[0].w = f2b(fa.w);
                pk.u[1].x = f2b(fb.x); pk.u[1].y = f2b(fb.y);
                pk.u[1].z = f2b(fb.z); pk.u[1].w = f2b(fb.w);
                *(uint4*)&As[ar][ah + j * 8] = pk.v;
            }
        } else {
#pragma unroll
            for (int j = 0; j < 4; j++)
                *(uint4*)&As[ar][ah + j * 8] = *(const uint4*)(ga + k0 + j * 8);
        }
#pragma unroll
        for (int j = 0; j < 2; j++)
            *(uint4*)&Bs[bn][bq + j * 8] = *(const uint4*)(gb + k0 + j * 8);
        __syncthreads();
#pragma unroll
        for (int kk = 0; kk < 64; kk += 32) {
            bf16x8 a[2], b[4];
#pragma unroll
            for (int m = 0; m < 2; m++)
                a[m] = *(const bf16x8*)&As[wid * 32 + m * 16 + fr][kk + kf];
#pragma unroll
            for (int n = 0; n < 4; n++)
                b[n] = *(const bf16x8*)&Bs[n * 16 + fr][kk + kf];
#pragma unroll
            for (int m = 0; m < 2; m++)
#pragma unroll
                for (int n = 0; n < 4; n++)
                    acc[m][n] = __builtin_amdgcn_mfma_f32_16x16x32_bf16(a[m], b[n], acc[m][n], 0, 0, 0);
        }
        __syncthreads();
    }

    // ---- fused alpha reduction (register-level, before LDS reuse) ----
    int rbase = r0 + wid * 32 + (lane >> 4) * 4;
    int cbase = n0 + fr;
    int head = n0 >> 6;
    float asv[4], adv[4];
#pragma unroll
    for (int n = 0; n < 4; n++) {
        asv[n] = a_s[cbase + n * 16];
        adv[n] = a_d[cbase + n * 16];
    }
#pragma unroll
    for (int m = 0; m < 2; m++)
#pragma unroll
        for (int q = 0; q < 4; q++) {
            int gr = rbase + m * 16 + q;
            float vs = 0.f, vd = 0.f;
#pragma unroll
            for (int n = 0; n < 4; n++) {
                float v = acc[m][n][q];
                vs += v * asv[n];
                vd += v * adv[n];
            }
#pragma unroll
            for (int o = 8; o > 0; o >>= 1) {
                vs += __shfl_xor(vs, o);
                vd += __shfl_xor(vd, o);
            }
            if (fr == 0 && gr < M) {
                als[gr * NHEAD + head] = vs;
                ald[gr * NHEAD + head] = vd;
            }
        }

    // ---- C store: LDS bounce (reuse As; [128][68] pad -> conflict-free) ----
    unsigned short (*Cs)[68] = (unsigned short(*)[68])&As[0][0];
    int lr0 = wid * 32 + (lane >> 4) * 4;
#pragma unroll
    for (int m = 0; m < 2; m++)
#pragma unroll
        for (int q = 0; q < 4; q++)
#pragma unroll
            for (int n = 0; n < 4; n++)
                Cs[lr0 + m * 16 + q][fr + n * 16] = f2b(acc[m][n][q]);
    __syncthreads();
    int tr = t >> 4;
    int tc = (t & 15) * 4;
#pragma unroll
    for (int rr = 0; rr < 8; rr++) {
        int lr = tr + rr * 16;
        int gr = r0 + lr;
        if (gr < M) *(ushort4*)(Cb + (size_t)gr * HDIM + n0 + tc) = *(const ushort4*)&Cs[lr][tc];
    }
}

// ---- agg: one WAVE per node; (src,e) of first 2 chunks cached in registers ----
__global__ __launch_bounds__(256) void agg_kernel(const unsigned short* __restrict__ projb,
                                                  const float* __restrict__ als,
                                                  const float* __restrict__ ald,
                                                  const int* __restrict__ indptr,
                                                  const int* __restrict__ esrc,
                                                  const float* __restrict__ bias,
                                                  unsigned short* __restrict__ featb) {
    int wid = threadIdx.x >> 6;
    int v = blockIdx.x * 4 + wid;
    if (v >= NN) return;
    int lane = threadIdx.x & 63;
    int h = lane >> 4;
    int sub = lane & 15;
    int beg = indptr[v], end = indptr[v + 1];
    float adv = ald[v * NHEAD + h];

    // ---- phase 1: online (max,sumexp); cache (s,e) for first 2 chunks ----
    float e0 = 0.f, e1 = 0.f;
    int s0r = 0, s1r = 0;
    float m = -INFINITY, ss = 0.f;
    int idx = 0;
    for (int i = beg + sub; i < end; i += 16, idx++) {
        int s = esrc[i];
        float e = als[s * NHEAD + h] + adv;
        e = e > 0.f ? e : NEG * e;
        if (idx == 0) { e0 = e; s0r = s; }
        else if (idx == 1) { e1 = e; s1r = s; }
        if (e > m) {
            ss = ss * __expf(m - e) + 1.f;
            m = e;
        } else {
            ss += __expf(e - m);
        }
    }
#pragma unroll
    for (int o = 8; o > 0; o >>= 1) {
        float m2 = __shfl_xor(m, o);
        float s2 = __shfl_xor(ss, o);
        float mn = fmaxf(m, m2);
        float a = (m == mn) ? ss : ss * __expf(m - mn);
        float b = (m2 == mn) ? s2 : s2 * __expf(m2 - mn);
        m = mn;
        ss = a + b;
    }
    float inv = 1.f / (ss + 1e-16f);

    float4 acc = make_float4(0.f, 0.f, 0.f, 0.f);
    int c = beg;
    int chunk = 0;
    // ---- full chunks: cached (s,e) for chunks 0/1 -> no leading loads ----
    for (; c + 16 <= end; c += 16, chunk++) {
        int sreg;
        float eC;
        if (chunk == 0) { sreg = s0r; eC = e0; }
        else if (chunk == 1) { sreg = s1r; eC = e1; }
        else {
            sreg = esrc[c + sub];
            eC = als[sreg * NHEAD + h] + adv;
            eC = eC > 0.f ? eC : NEG * eC;
        }
        float wreg = __expf(eC - m) * inv;

        ushort4 p[16];
#pragma unroll
        for (int j = 0; j < 16; j++) {
            int s = __shfl(sreg, j);
            p[j] = *(const ushort4*)(projb + (size_t)s * HDIM + (lane << 2));
        }
#pragma unroll
        for (int j = 0; j < 16; j++) {
            float w = __shfl(wreg, (h << 4) | j);
            acc.x += b2f(p[j].x) * w;
            acc.y += b2f(p[j].y) * w;
            acc.z += b2f(p[j].z) * w;
            acc.w += b2f(p[j].w) * w;
        }
    }
    // ---- ragged tail ----
    int n = end - c;
    if (n > 0) {
        int sreg;
        float eT;
        if (chunk == 0) { sreg = s0r; eT = e0; }
        else if (chunk == 1) { sreg = s1r; eT = e1; }
        else {
            sreg = (sub < n) ? esrc[c + sub] : 0;
            eT = als[sreg * NHEAD + h] + adv;
            eT = eT > 0.f ? eT : NEG * eT;
        }
        float wreg = (sub < n) ? __expf(eT - m) * inv : 0.f;
        for (int j = 0; j < n; j++) {
            float w = __shfl(wreg, (h << 4) | j);
            int s = __shfl(sreg, j);
            const ushort4 p = *(const ushort4*)(projb + (size_t)s * HDIM + (lane << 2));
            acc.x += b2f(p.x) * w;
            acc.y += b2f(p.y) * w;
            acc.z += b2f(p.z) * w;
            acc.w += b2f(p.w) * w;
        }
    }

    const float4 b4 = *(const float4*)(bias + (lane << 2));
    float4 r;
    r.x = acc.x + b4.x;
    r.y = acc.y + b4.y;
    r.z = acc.z + b4.z;
    r.w = acc.w + b4.w;
    r.x = r.x > 0.f ? r.x : __expf(r.x) - 1.f;
    r.y = r.y > 0.f ? r.y : __expf(r.y) - 1.f;
    r.z = r.z > 0.f ? r.z : __expf(r.z) - 1.f;
    r.w = r.w > 0.f ? r.w : __expf(r.w) - 1.f;
    ushort4 o4;
    o4.x = f2b(r.x); o4.y = f2b(r.y); o4.z = f2b(r.z); o4.w = f2b(r.w);
    *(ushort4*)(featb + (size_t)v * HDIM + (lane << 2)) = o4;
}

// ---- final linear [256->40] + log_softmax (bf16 features), class dim padded to 64 ----
__global__ __launch_bounds__(256) void final_kernel(const unsigned short* __restrict__ featb,
                                                    const float* __restrict__ Wl,
                                                    const float* __restrict__ bl,
                                                    float* __restrict__ out) {
    const int BK = 16;
    __shared__ float As[BK][65];
    __shared__ float Bs[BK][65];
    int tx = threadIdx.x & 15, ty = threadIdx.x >> 4;
    int row0 = blockIdx.x * 64;
    float acc[4][4] = {};
    for (int k0 = 0; k0 < HDIM; k0 += BK) {
#pragma unroll
        for (int i = 0; i < 4; i++) {
            int l = threadIdx.x + 256 * i;
            int r = l >> 4, c = l & 15;
            int gr = row0 + r;
            float v = 0.f;
            if (gr < NN) v = b2f(featb[(size_t)gr * HDIM + k0 + c]);
            As[c][r] = v;
        }
#pragma unroll
        for (int i = 0; i < 4; i++) {
            int l = threadIdx.x + 256 * i;
            int r = l >> 6, c = l & 63;
            Bs[r][c] = (c < NCLS) ? Wl[(size_t)(k0 + r) * NCLS + c] : 0.f;
        }
        __syncthreads();
#pragma unroll
        for (int k = 0; k < BK; k++) {
            float a[4], b[4];
#pragma unroll
            for (int i = 0; i < 4; i++) a[i] = As[k][ty + 16 * i];
#pragma unroll
            for (int j = 0; j < 4; j++) b[j] = Bs[k][tx + 16 * j];
#pragma unroll
            for (int i = 0; i < 4; i++)
#pragma unroll
                for (int j = 0; j < 4; j++) acc[i][j] += a[i] * b[j];
        }
        __syncthreads();
    }
    float b0 = bl[tx], b1 = bl[tx + 16], b2 = (tx < 8) ? bl[tx + 32] : 0.f;
#pragma unroll
    for (int i = 0; i < 4; i++) {
        int gr = row0 + ty + 16 * i;
        if (gr >= NN) continue;
        float l0 = acc[i][0] + b0;
        float l1 = acc[i][1] + b1;
        float l2 = (tx < 8) ? acc[i][2] + b2 : -INFINITY;
        float m = fmaxf(fmaxf(l0, l1), l2);
#pragma unroll
        for (int o = 8; o > 0; o >>= 1) m = fmaxf(m, __shfl_xor(m, o));
        float s = __expf(l0 - m) + __expf(l1 - m) + ((tx < 8) ? __expf(l2 - m) : 0.f);
#pragma unroll
        for (int o = 8; o > 0; o >>= 1) s += __shfl_xor(s, o);
        float lse = m + __logf(s);
        out[(size_t)gr * NCLS + tx] = l0 - lse;
        out[(size_t)gr * NCLS + tx + 16] = l1 - lse;
        if (tx < 8) out[(size_t)gr * NCLS + tx + 32] = l2 - lse;
    }
}

extern "C" void kernel_launch(void* const* d_in, const int* in_sizes, int n_in,
                              void* d_out, int out_size, void* d_ws, size_t ws_size,
                              hipStream_t stream) {
    const float* x  = (const float*)d_in[0];
    const int* ei32 = (const int*)d_in[1];
    const float* W1 = (const float*)d_in[2];
    const float* as1 = (const float*)d_in[3];
    const float* ad1 = (const float*)d_in[4];
    const float* b1 = (const float*)d_in[5];
    const float* W2 = (const float*)d_in[6];
    const float* as2 = (const float*)d_in[7];
    const float* ad2 = (const float*)d_in[8];
    const float* b2 = (const float*)d_in[9];
    const float* W3 = (const float*)d_in[10];
    const float* as3 = (const float*)d_in[11];
    const float* ad3 = (const float*)d_in[12];
    const float* b3 = (const float*)d_in[13];
    const float* Wl = (const float*)d_in[14];
    const float* bl = (const float*)d_in[15];
    float* out = (float*)d_out;

    // workspace layout
    char* w = (char*)d_ws;
    unsigned short* projb = (unsigned short*)w;  w += (size_t)NN * HDIM * 2;
    unsigned short* featb = (unsigned short*)w;  w += (size_t)NN * HDIM * 2;
    unsigned short* Wt1b  = (unsigned short*)w;  w += (size_t)HDIM * FIN * 2;
    unsigned short* Wt2b  = (unsigned short*)w;  w += (size_t)HDIM * HDIM * 2;
    unsigned short* Wt3b  = (unsigned short*)w;  w += (size_t)HDIM * HDIM * 2;
    float* als  = (float*)w;  w += (size_t)NN * NHEAD * 4;
    float* ald  = (float*)w;  w += (size_t)NN * NHEAD * 4;
    int* deg    = (int*)w;    w += (size_t)NN * 4;
    int* incl   = (int*)w;    w += (size_t)NN * 4;
    int* bsum   = (int*)w;    w += 256 * 4;
    int* indptr = (int*)w;    w += (size_t)(NN + 1) * 4;
    int* cursor = (int*)w;    w += (size_t)NN * 4;
    int* esrc   = (int*)w;    w += (size_t)ET * 4;
    int* flag   = (int*)w;    w += 64;

    // ---- one-time conversions (batched; x conversion fused into layer-1 GEMM) ----
    wconv3_kernel<<<dim3(8, 8, 3), 256, 0, stream>>>(W1, W2, W3, Wt1b, Wt2b, Wt3b);

    // ---- CSR build (same edge structure for all three layers) ----
    hipMemsetAsync(deg, 0, (size_t)NN * 4, stream);
    detect_kernel<<<1, 64, 0, stream>>>(ei32, flag);
    deg_kernel<<<(ET + 255) / 256, 256, 0, stream>>>(ei32, flag, deg);
    scan1<<<NB_SCAN, 256, 0, stream>>>(deg, incl, bsum);
    scan2<<<1, 256, 0, stream>>>(bsum);
    scan3<<<NB_SCAN, 256, 0, stream>>>(incl, bsum, deg, indptr, cursor);
    fill_kernel<<<(ET + 255) / 256, 256, 0, stream>>>(ei32, flag, cursor, esrc);

    // XCD-swizzled 1D gemm grid: 391 row-panels padded to 392 (49 groups of 8) x 4 col-blocks
    int ggrid = 8 * 4 * (((NN + 127) / 128 + 7) / 8);   // 1568
    int agrid = (NN + 3) / 4;

    // ---- layer 1 (A = f32 x, converted in staging) ----
    gemm_mfma<<<ggrid, 256, 0, stream>>>((const unsigned short*)0, x, Wt1b, projb, as1, ad1, als, ald, NN, FIN);
    agg_kernel<<<agrid, 256, 0, stream>>>(projb, als, ald, indptr, esrc, b1, featb);
    // ---- layer 2 ----
    gemm_mfma<<<ggrid, 256, 0, stream>>>(featb, (const float*)0, Wt2b, projb, as2, ad2, als, ald, NN, HDIM);
    agg_kernel<<<agrid, 256, 0, stream>>>(projb, als, ald, indptr, esrc, b2, featb);
    // ---- layer 3 ----
    gemm_mfma<<<ggrid, 256, 0, stream>>>(featb, (const float*)0, Wt3b, projb, as3, ad3, als, ald, NN, HDIM);
    agg_kernel<<<agrid, 256, 0, stream>>>(projb, als, ald, indptr, esrc, b3, featb);
    // ---- final linear + log_softmax (fused) ----
    final_kernel<<<(NN + 63) / 64, 256, 0, stream>>>(featb, Wl, bl, out);
}